// Round 16
// baseline (140.185 us; speedup 1.0000x reference)
//
#include <hip/hip_runtime.h>
#include <hip/hip_bf16.h>

#define NN 4096
#define IN_DIM 512
#define OUT_DIM 256
#define NH 4
#define HD 64
#define NEG_SLOPE 0.2f
#define LN_EPS 1e-5f
#define LOG2E 1.4426950408889634f
#define MDC 8.0f   // constant softmax stabilizer (log2 domain); valid upper bound

typedef __attribute__((ext_vector_type(8))) short short8;
typedef __attribute__((ext_vector_type(4))) float f32x4;
typedef unsigned short u16;
typedef unsigned int u32;
typedef unsigned char u8;

// ---------------------------------------------------------------------------
// K0: transpose W [H][K][D] f32 -> Wt [h*64+d][512] bf16 (1 elem/thread).
// ---------------------------------------------------------------------------
__global__ __launch_bounds__(1024) void k0_wt(
    const float* __restrict__ W, u16* __restrict__ Wt)
{
  const int n = blockIdx.x * 1024 + threadIdx.x;   // n = h*2^15 + k*2^6 + d
  const int d = n & 63;
  const int k = (n >> 6) & 511;
  const int h = n >> 15;
  __hip_bfloat16 bv = __float2bfloat16(W[n]);
  Wt[(size_t)(h * HD + d) * IN_DIM + k] = *reinterpret_cast<const u16*>(&bv);
}

// ---------------------------------------------------------------------------
// K1: MFMA projection + adj->mask pack via WAVE SPECIALIZATION.
// [round-15 verified] grid 256, block 512 = 8 waves: waves 0-3 MFMA+scores,
// waves 4-7 streaming pack.
// ---------------------------------------------------------------------------
__global__ __launch_bounds__(512) void k1_proj(
    const float* __restrict__ x, const u16* __restrict__ Wt,
    const float* __restrict__ a, const int* __restrict__ adj,
    u16* __restrict__ WxT,
    float* __restrict__ s_src,
    float* __restrict__ d_dst,
    u8* __restrict__ mask)
{
  const int i0 = blockIdx.x * 16;
  const int t = threadIdx.x;
  const int wv = t >> 6;
  const int lane = t & 63;
  const int rloc = lane & 15;
  const int g = lane >> 4;

  __shared__ u16 xl[16 * 512];   // [row][unit*8], units XOR-swizzled by row&7

  // ---- stage x tile: 1024 (row,unit) pairs over 512 threads x 2 passes ----
#pragma unroll
  for (int p = 0; p < 2; ++p) {
    const int n = p * 512 + t;
    const int r = n >> 6;
    const int u = n & 63;
    const float* xr = x + (size_t)(i0 + r) * IN_DIM + u * 8;
    const float4 lo = *reinterpret_cast<const float4*>(xr);
    const float4 hi = *reinterpret_cast<const float4*>(xr + 4);
    const float fv[8] = {lo.x, lo.y, lo.z, lo.w, hi.x, hi.y, hi.z, hi.w};
    u16 us[8];
#pragma unroll
    for (int e = 0; e < 8; ++e) {
      __hip_bfloat16 bv = __float2bfloat16(fv[e]);
      us[e] = *reinterpret_cast<const u16*>(&bv);
    }
    const int phys = (u & 56) | ((u & 7) ^ (r & 7));
    uint4 pk;
    pk.x = (u32)us[0] | ((u32)us[1] << 16);
    pk.y = (u32)us[2] | ((u32)us[3] << 16);
    pk.z = (u32)us[4] | ((u32)us[5] << 16);
    pk.w = (u32)us[6] | ((u32)us[7] << 16);
    *reinterpret_cast<uint4*>(&xl[r * 512 + phys * 8]) = pk;
  }
  __syncthreads();

  if (wv >= 4) {
    // ---- pack waves: rows i0..i0+15, thread t2 covers cols [t2*16, +16) ----
    const int t2 = t - 256;
    const int j0 = t2 * 16;
#pragma unroll
    for (int rr = 0; rr < 16; ++rr) {
      const int row = i0 + rr;
      const int* ap = adj + (size_t)row * NN + j0;
      u32 bb = 0;
#pragma unroll
      for (int q = 0; q < 4; ++q) {
        const int4 v = *reinterpret_cast<const int4*>(ap + q * 4);
        const int vj = j0 + q * 4;
        if ((v.x > 0) || (row == vj))     bb |= 1u << (q * 4);
        if ((v.y > 0) || (row == vj + 1)) bb |= 1u << (q * 4 + 1);
        if ((v.z > 0) || (row == vj + 2)) bb |= 1u << (q * 4 + 2);
        if ((v.w > 0) || (row == vj + 3)) bb |= 1u << (q * 4 + 3);
      }
      *reinterpret_cast<u16*>(mask + (size_t)row * (NN / 8) + t2 * 2) = (u16)bb;
    }
    return;
  }

  // ---- compute waves: round-7 verified MFMA + scores (wave = head) ----
  const int h = wv;
  f32x4 acc[4] = {};
  const u16* wb = Wt + (size_t)(h * HD + rloc) * IN_DIM;
#pragma unroll
  for (int ks = 0; ks < 16; ++ks) {
    const int u = ks * 4 + g;
    const int phys = (u & 56) | ((u & 7) ^ (rloc & 7));
    const short8 af = *reinterpret_cast<const short8*>(&xl[rloc * 512 + phys * 8]);
#pragma unroll
    for (int dt = 0; dt < 4; ++dt) {
      const short8 bf = *reinterpret_cast<const short8*>(
          wb + (size_t)dt * 16 * IN_DIM + ks * 32 + g * 8);
      acc[dt] = __builtin_amdgcn_mfma_f32_16x16x32_bf16(af, bf, acc[dt], 0, 0, 0);
    }
  }

  // ---- epilogue: direct WxT store + scores ----
#pragma unroll
  for (int dt = 0; dt < 4; ++dt) {
    u16 us[4];
#pragma unroll
    for (int q = 0; q < 4; ++q) {
      __hip_bfloat16 bv = __float2bfloat16(acc[dt][q]);
      us[q] = *reinterpret_cast<const u16*>(&bv);
    }
    ushort4 pk = {us[0], us[1], us[2], us[3]};
    *reinterpret_cast<ushort4*>(
        WxT + (size_t)(h * HD + dt * 16 + rloc) * NN + i0 + g * 4) = pk;
  }

  float as_v[4], ad_v[4];
#pragma unroll
  for (int dt = 0; dt < 4; ++dt) {
    as_v[dt] = a[(size_t)h * 2 * HD + dt * 16 + rloc];
    ad_v[dt] = a[(size_t)h * 2 * HD + HD + dt * 16 + rloc];
  }
  float sv[4], dv[4];
#pragma unroll
  for (int q = 0; q < 4; ++q) {
    float s = 0.f, d = 0.f;
#pragma unroll
    for (int dt = 0; dt < 4; ++dt) {
      s = fmaf(acc[dt][q], as_v[dt], s);
      d = fmaf(acc[dt][q], ad_v[dt], d);
    }
    sv[q] = s; dv[q] = d;
  }
#pragma unroll
  for (int mm = 8; mm >= 1; mm >>= 1) {
#pragma unroll
    for (int q = 0; q < 4; ++q) {
      sv[q] += __shfl_xor(sv[q], mm);
      dv[q] += __shfl_xor(dv[q], mm);
    }
  }
  if (rloc == 0) {
#pragma unroll
    for (int q = 0; q < 4; ++q) {
      const int i = i0 + g * 4 + q;
      s_src[(size_t)h * NN + i] = sv[q] * LOG2E;
      d_dst[(size_t)h * NN + i] = dv[q] * LOG2E;
    }
  }
}

// ---------------------------------------------------------------------------
// K3: masked rank-1 softmax via block-local E-tables + PV (bf16 MFMA),
// LDS-staged & double-buffered. Mask words read DIRECTLY from L2 with
// 1-tile-ahead prefetch (no mk LDS staging) -> LDS 40 KB -> 3-4 blocks/CU.
// grid (16 i-blocks, 4 heads, 4 j-quarters), block 512 = 8 waves x 32 rows.
// ---------------------------------------------------------------------------
__global__ __launch_bounds__(512, 6) void k3_attn(
    const u8* __restrict__ mask,
    const u16* __restrict__ WxT,
    const float* __restrict__ s_src, const float* __restrict__ d_dst,
    u16* __restrict__ Pp, float* __restrict__ Sp)
{
  const int bx = blockIdx.x;
  const int h = blockIdx.y;
  const int jq = blockIdx.z;
  const int t = threadIdx.x;
  const int wv = t >> 6;
  const int lane = t & 63;
  const int rloc = lane & 15;
  const int g = lane >> 4;
  const int i_base = bx * 256 + wv * 32;

  __shared__ u16 wt[2][64 * 128];   // [buf][row*128 + unit*8], XOR-swizzled
  __shared__ float el[1024 * 2];    // (E1,E2) interleaved, 8 KiB

  const float md = MDC;
  const float si0 = s_src[(size_t)h * NN + i_base + rloc];
  const float si1 = s_src[(size_t)h * NN + i_base + 16 + rloc];
  const float e00 = si0 + md, e01 = si1 + md;
  const float m0 = fmaxf(e00, NEG_SLOPE * e00);
  const float m1 = fmaxf(e01, NEG_SLOPE * e01);
  const float sa0 = si0 - m0, sb0 = fmaf(NEG_SLOPE, si0, -m0);
  const float sa1 = si1 - m1, sb1 = fmaf(NEG_SLOPE, si1, -m1);
  float c1_0, c2_0, c1_1, c2_1;
  asm("v_exp_f32 %0, %1" : "=v"(c1_0) : "v"(sa0));
  asm("v_exp_f32 %0, %1" : "=v"(c2_0) : "v"(sb0));
  asm("v_exp_f32 %0, %1" : "=v"(c1_1) : "v"(sa1));
  asm("v_exp_f32 %0, %1" : "=v"(c2_1) : "v"(sb1));

  const u16* wsrc = WxT + (size_t)(h * HD) * NN + jq * 1024;
  // per-row mask pointers (16 B per tile, L2-resident)
  const u8* mrow0 = mask + (size_t)(i_base + rloc) * (NN / 8) + jq * 128;
  const u8* mrow1 = mask + (size_t)(i_base + 16 + rloc) * (NN / 8) + jq * 128;

  const int r0 = t >> 4;
  const int un = t & 15;
  const int up = un ^ (r0 & 7);

  // ---- prologue: E-table gen + WxT tile 0 + mask tile 0 ----
#pragma unroll
  for (int p = 0; p < 2; ++p) {
    const int j = p * 512 + t;
    const float dj = d_dst[(size_t)h * NN + jq * 1024 + j];
    const float djs = dj * NEG_SLOPE;
    float e1, e2;
    asm("v_exp_f32 %0, %1" : "=v"(e1) : "v"(dj));    // 2^dj
    asm("v_exp_f32 %0, %1" : "=v"(e2) : "v"(djs));   // 2^(0.2 dj)
    el[j * 2] = e1;
    el[j * 2 + 1] = e2;
  }
  {
    const uint4 s0 = *reinterpret_cast<const uint4*>(wsrc + (size_t)r0 * NN + un * 8);
    const uint4 s1 = *reinterpret_cast<const uint4*>(wsrc + (size_t)(r0 + 32) * NN + un * 8);
    *reinterpret_cast<uint4*>(&wt[0][r0 * 128 + up * 8]) = s0;
    *reinterpret_cast<uint4*>(&wt[0][(r0 + 32) * 128 + up * 8]) = s1;
  }
  uint4 mq0 = *reinterpret_cast<const uint4*>(mrow0);
  uint4 mq1 = *reinterpret_cast<const uint4*>(mrow1);
  __syncthreads();

  f32x4 acc0[4] = {}, acc1[4] = {};
  f32x4 accs0 = {}, accs1 = {};
  short8 ones;
#pragma unroll
  for (int e = 0; e < 8; ++e) ones[e] = (short)0x3F80;

  int buf = 0;
  for (int tile = 0; tile < 8; ++tile) {
    uint4 n0, n1, mn0, mn1;
    const bool pf = (tile < 7);
    if (pf) {
      n0 = *reinterpret_cast<const uint4*>(
          wsrc + (size_t)r0 * NN + (tile + 1) * 128 + un * 8);
      n1 = *reinterpret_cast<const uint4*>(
          wsrc + (size_t)(r0 + 32) * NN + (tile + 1) * 128 + un * 8);
      mn0 = *reinterpret_cast<const uint4*>(mrow0 + (tile + 1) * 16);
      mn1 = *reinterpret_cast<const uint4*>(mrow1 + (tile + 1) * 16);
    }

#pragma unroll
    for (int ks = 0; ks < 4; ++ks) {
      short8 bfr[4];
#pragma unroll
      for (int dt = 0; dt < 4; ++dt) {
        const int row = dt * 16 + rloc;
        const int unit = (ks * 4 + g) ^ (row & 7);
        bfr[dt] = *reinterpret_cast<const short8*>(&wt[buf][row * 128 + unit * 8]);
      }
      const int jloc = tile * 128 + ks * 32 + g * 8;
      const float* eb = &el[2 * jloc];
      const float4 Ea = *reinterpret_cast<const float4*>(eb);
      const float4 Eb = *reinterpret_cast<const float4*>(eb + 4);
      const float4 Ec = *reinterpret_cast<const float4*>(eb + 8);
      const float4 Ed = *reinterpret_cast<const float4*>(eb + 12);
      const float E1v[8] = {Ea.x, Ea.z, Eb.x, Eb.z, Ec.x, Ec.z, Ed.x, Ed.z};
      const float E2v[8] = {Ea.y, Ea.w, Eb.y, Eb.w, Ec.y, Ec.w, Ed.y, Ed.w};
      const u32 mw0 = (ks == 0) ? mq0.x : (ks == 1) ? mq0.y : (ks == 2) ? mq0.z : mq0.w;
      const u32 mw1 = (ks == 0) ? mq1.x : (ks == 1) ? mq1.y : (ks == 2) ? mq1.z : mq1.w;
      const u32 mb0 = (mw0 >> (g * 8)) & 0xffu;
      const u32 mb1 = (mw1 >> (g * 8)) & 0xffu;
      short8 af0, af1;
#pragma unroll
      for (int e = 0; e < 8; ++e) {
        float p0 = fmaxf(c1_0 * E1v[e], c2_0 * E2v[e]);
        float p1 = fmaxf(c1_1 * E1v[e], c2_1 * E2v[e]);
        p0 = (mb0 & (1u << e)) ? p0 : 0.f;
        p1 = (mb1 & (1u << e)) ? p1 : 0.f;
        __hip_bfloat16 b0 = __float2bfloat16(p0);
        __hip_bfloat16 b1 = __float2bfloat16(p1);
        af0[e] = *reinterpret_cast<const short*>(&b0);
        af1[e] = *reinterpret_cast<const short*>(&b1);
      }
#pragma unroll
      for (int dt = 0; dt < 4; ++dt) {
        acc0[dt] = __builtin_amdgcn_mfma_f32_16x16x32_bf16(af0, bfr[dt], acc0[dt], 0, 0, 0);
        acc1[dt] = __builtin_amdgcn_mfma_f32_16x16x32_bf16(af1, bfr[dt], acc1[dt], 0, 0, 0);
      }
      accs0 = __builtin_amdgcn_mfma_f32_16x16x32_bf16(af0, ones, accs0, 0, 0, 0);
      accs1 = __builtin_amdgcn_mfma_f32_16x16x32_bf16(af1, ones, accs1, 0, 0, 0);
    }

    if (pf) {
      *reinterpret_cast<uint4*>(&wt[buf ^ 1][r0 * 128 + up * 8]) = n0;
      *reinterpret_cast<uint4*>(&wt[buf ^ 1][(r0 + 32) * 128 + up * 8]) = n1;
      mq0 = mn0;
      mq1 = mn1;
    }
    __syncthreads();
    buf ^= 1;
  }

  u16* Pb = Pp + (size_t)jq * NN * OUT_DIM;
#pragma unroll
  for (int dt = 0; dt < 4; ++dt)
#pragma unroll
    for (int q = 0; q < 4; ++q) {
      __hip_bfloat16 v0 = __float2bfloat16(acc0[dt][q]);
      __hip_bfloat16 v1 = __float2bfloat16(acc1[dt][q]);
      Pb[(size_t)(i_base + g * 4 + q) * OUT_DIM + h * HD + dt * 16 + rloc] =
          *reinterpret_cast<const u16*>(&v0);
      Pb[(size_t)(i_base + 16 + g * 4 + q) * OUT_DIM + h * HD + dt * 16 + rloc] =
          *reinterpret_cast<const u16*>(&v1);
    }
  if (rloc == 0) {
    *reinterpret_cast<f32x4*>(&Sp[((size_t)jq * NH + h) * NN + i_base + g * 4]) = accs0;
    *reinterpret_cast<f32x4*>(&Sp[((size_t)jq * NH + h) * NN + i_base + 16 + g * 4]) = accs1;
  }
}

// ---------------------------------------------------------------------------
// K4: merge 4 j-quarter partials, normalize, ELU, LayerNorm, store.
// [round-7 verified]
// ---------------------------------------------------------------------------
__global__ __launch_bounds__(256) void k4_final(
    const u16* __restrict__ Pp, const float* __restrict__ Sp,
    const float* __restrict__ gamma, const float* __restrict__ beta,
    float* __restrict__ out)
{
  const int i0 = blockIdx.x * 16;
  const int t = threadIdx.x;
  const int wv = t >> 6;
  const int lane = t & 63;
  const int c0 = lane * 4;
  const int h = lane >> 4;

  const float4 gm = *reinterpret_cast<const float4*>(gamma + c0);
  const float4 bt = *reinterpret_cast<const float4*>(beta + c0);

  for (int rr = 0; rr < 4; ++rr) {
    const int i = i0 + wv * 4 + rr;
    float v[4] = {0.f, 0.f, 0.f, 0.f};
    float denom = 0.f;
#pragma unroll
    for (int q = 0; q < 4; ++q) {
      const ushort4 pv = *reinterpret_cast<const ushort4*>(
          Pp + (size_t)q * NN * OUT_DIM + (size_t)i * OUT_DIM + c0);
      v[0] += __uint_as_float((u32)pv.x << 16);
      v[1] += __uint_as_float((u32)pv.y << 16);
      v[2] += __uint_as_float((u32)pv.z << 16);
      v[3] += __uint_as_float((u32)pv.w << 16);
      denom += Sp[((size_t)q * NH + h) * NN + i];
    }
    const float inv = 1.f / denom;
    float sum = 0.f, sq = 0.f;
#pragma unroll
    for (int q2 = 0; q2 < 4; ++q2) {
      float xx = v[q2] * inv;
      xx = (xx > 0.f) ? xx : expm1f(xx);
      v[q2] = xx;
      sum += xx;
      sq += xx * xx;
    }
#pragma unroll
    for (int mm = 32; mm >= 1; mm >>= 1) {
      sum += __shfl_xor(sum, mm);
      sq += __shfl_xor(sq, mm);
    }
    const float mu = sum * (1.f / OUT_DIM);
    const float var = sq * (1.f / OUT_DIM) - mu * mu;
    const float rs = rsqrtf(var + LN_EPS);
    float4 o;
    o.x = (v[0] - mu) * rs * gm.x + bt.x;
    o.y = (v[1] - mu) * rs * gm.y + bt.y;
    o.z = (v[2] - mu) * rs * gm.z + bt.z;
    o.w = (v[3] - mu) * rs * gm.w + bt.w;
    *reinterpret_cast<float4*>(out + (size_t)i * OUT_DIM + c0) = o;
  }
}

extern "C" void kernel_launch(void* const* d_in, const int* in_sizes, int n_in,
                              void* d_out, int out_size, void* d_ws, size_t ws_size,
                              hipStream_t stream) {
  const float* x = (const float*)d_in[0];
  const int* adj = (const int*)d_in[1];
  const float* W = (const float*)d_in[2];
  const float* a = (const float*)d_in[3];
  const float* gamma = (const float*)d_in[4];
  const float* beta = (const float*)d_in[5];
  float* out = (float*)d_out;

  char* ws = (char*)d_ws;
  size_t off = 0;
  u16* WxT = (u16*)(ws + off);        off += (size_t)NH * HD * NN * 2;          // 2 MiB
  float* s_src = (float*)(ws + off);  off += (size_t)NH * NN * 4;               // 64 KiB
  float* d_dst = (float*)(ws + off);  off += (size_t)NH * NN * 4;               // 64 KiB
  u8* mask = (u8*)(ws + off);         off += (size_t)NN * (NN / 8);             // 2 MiB
  u16* Pp = (u16*)(ws + off);         off += (size_t)4 * NN * OUT_DIM * 2;      // 8 MiB (bf16)
  float* Sp = (float*)(ws + off);     off += (size_t)4 * NH * NN * 4;           // 256 KiB
  u16* Wt = (u16*)(ws + off);         off += (size_t)NH * HD * IN_DIM * 2;      // 256 KiB

  k0_wt<<<dim3(128), dim3(1024), 0, stream>>>(W, Wt);
  k1_proj<<<dim3(256), dim3(512), 0, stream>>>(x, Wt, a, adj, WxT, s_src,
                                               d_dst, mask);
  k3_attn<<<dim3(16, NH, 4), dim3(512), 0, stream>>>(mask, WxT, s_src, d_dst,
                                                     Pp, Sp);
  k4_final<<<dim3(256), dim3(256), 0, stream>>>(Pp, Sp, gamma, beta, out);
}

// Round 17
// 59.476 us; speedup vs baseline: 2.3570x; 2.3570x over previous
//
#include <hip/hip_runtime.h>
#include <hip/hip_bf16.h>

#define NN 4096
#define IN_DIM 512
#define OUT_DIM 256
#define NH 4
#define HD 64
#define NEG_SLOPE 0.2f
#define LN_EPS 1e-5f
#define LOG2E 1.4426950408889634f
#define MDC 8.0f   // constant softmax stabilizer (log2 domain); valid upper bound

typedef __attribute__((ext_vector_type(8))) short short8;
typedef __attribute__((ext_vector_type(4))) float f32x4;
typedef unsigned short u16;
typedef unsigned int u32;
typedef unsigned char u8;

// ---------------------------------------------------------------------------
// K0: transpose W [H][K][D] f32 -> Wt [h*64+d][512] bf16 (1 elem/thread).
// ---------------------------------------------------------------------------
__global__ __launch_bounds__(1024) void k0_wt(
    const float* __restrict__ W, u16* __restrict__ Wt)
{
  const int n = blockIdx.x * 1024 + threadIdx.x;   // n = h*2^15 + k*2^6 + d
  const int d = n & 63;
  const int k = (n >> 6) & 511;
  const int h = n >> 15;
  __hip_bfloat16 bv = __float2bfloat16(W[n]);
  Wt[(size_t)(h * HD + d) * IN_DIM + k] = *reinterpret_cast<const u16*>(&bv);
}

// ---------------------------------------------------------------------------
// K1: MFMA projection + adj->mask pack via WAVE SPECIALIZATION.
// [round-15 verified] grid 256, block 512 = 8 waves: waves 0-3 MFMA+scores,
// waves 4-7 streaming pack.
// ---------------------------------------------------------------------------
__global__ __launch_bounds__(512) void k1_proj(
    const float* __restrict__ x, const u16* __restrict__ Wt,
    const float* __restrict__ a, const int* __restrict__ adj,
    u16* __restrict__ WxT,
    float* __restrict__ s_src,
    float* __restrict__ d_dst,
    u8* __restrict__ mask)
{
  const int i0 = blockIdx.x * 16;
  const int t = threadIdx.x;
  const int wv = t >> 6;
  const int lane = t & 63;
  const int rloc = lane & 15;
  const int g = lane >> 4;

  __shared__ u16 xl[16 * 512];   // [row][unit*8], units XOR-swizzled by row&7

  // ---- stage x tile: 1024 (row,unit) pairs over 512 threads x 2 passes ----
#pragma unroll
  for (int p = 0; p < 2; ++p) {
    const int n = p * 512 + t;
    const int r = n >> 6;
    const int u = n & 63;
    const float* xr = x + (size_t)(i0 + r) * IN_DIM + u * 8;
    const float4 lo = *reinterpret_cast<const float4*>(xr);
    const float4 hi = *reinterpret_cast<const float4*>(xr + 4);
    const float fv[8] = {lo.x, lo.y, lo.z, lo.w, hi.x, hi.y, hi.z, hi.w};
    u16 us[8];
#pragma unroll
    for (int e = 0; e < 8; ++e) {
      __hip_bfloat16 bv = __float2bfloat16(fv[e]);
      us[e] = *reinterpret_cast<const u16*>(&bv);
    }
    const int phys = (u & 56) | ((u & 7) ^ (r & 7));
    uint4 pk;
    pk.x = (u32)us[0] | ((u32)us[1] << 16);
    pk.y = (u32)us[2] | ((u32)us[3] << 16);
    pk.z = (u32)us[4] | ((u32)us[5] << 16);
    pk.w = (u32)us[6] | ((u32)us[7] << 16);
    *reinterpret_cast<uint4*>(&xl[r * 512 + phys * 8]) = pk;
  }
  __syncthreads();

  if (wv >= 4) {
    // ---- pack waves: rows i0..i0+15, thread t2 covers cols [t2*16, +16) ----
    const int t2 = t - 256;
    const int j0 = t2 * 16;
#pragma unroll
    for (int rr = 0; rr < 16; ++rr) {
      const int row = i0 + rr;
      const int* ap = adj + (size_t)row * NN + j0;
      u32 bb = 0;
#pragma unroll
      for (int q = 0; q < 4; ++q) {
        const int4 v = *reinterpret_cast<const int4*>(ap + q * 4);
        const int vj = j0 + q * 4;
        if ((v.x > 0) || (row == vj))     bb |= 1u << (q * 4);
        if ((v.y > 0) || (row == vj + 1)) bb |= 1u << (q * 4 + 1);
        if ((v.z > 0) || (row == vj + 2)) bb |= 1u << (q * 4 + 2);
        if ((v.w > 0) || (row == vj + 3)) bb |= 1u << (q * 4 + 3);
      }
      *reinterpret_cast<u16*>(mask + (size_t)row * (NN / 8) + t2 * 2) = (u16)bb;
    }
    return;
  }

  // ---- compute waves: round-7 verified MFMA + scores (wave = head) ----
  const int h = wv;
  f32x4 acc[4] = {};
  const u16* wb = Wt + (size_t)(h * HD + rloc) * IN_DIM;
#pragma unroll
  for (int ks = 0; ks < 16; ++ks) {
    const int u = ks * 4 + g;
    const int phys = (u & 56) | ((u & 7) ^ (rloc & 7));
    const short8 af = *reinterpret_cast<const short8*>(&xl[rloc * 512 + phys * 8]);
#pragma unroll
    for (int dt = 0; dt < 4; ++dt) {
      const short8 bf = *reinterpret_cast<const short8*>(
          wb + (size_t)dt * 16 * IN_DIM + ks * 32 + g * 8);
      acc[dt] = __builtin_amdgcn_mfma_f32_16x16x32_bf16(af, bf, acc[dt], 0, 0, 0);
    }
  }

  // ---- epilogue: direct WxT store + scores ----
#pragma unroll
  for (int dt = 0; dt < 4; ++dt) {
    u16 us[4];
#pragma unroll
    for (int q = 0; q < 4; ++q) {
      __hip_bfloat16 bv = __float2bfloat16(acc[dt][q]);
      us[q] = *reinterpret_cast<const u16*>(&bv);
    }
    ushort4 pk = {us[0], us[1], us[2], us[3]};
    *reinterpret_cast<ushort4*>(
        WxT + (size_t)(h * HD + dt * 16 + rloc) * NN + i0 + g * 4) = pk;
  }

  float as_v[4], ad_v[4];
#pragma unroll
  for (int dt = 0; dt < 4; ++dt) {
    as_v[dt] = a[(size_t)h * 2 * HD + dt * 16 + rloc];
    ad_v[dt] = a[(size_t)h * 2 * HD + HD + dt * 16 + rloc];
  }
  float sv[4], dv[4];
#pragma unroll
  for (int q = 0; q < 4; ++q) {
    float s = 0.f, d = 0.f;
#pragma unroll
    for (int dt = 0; dt < 4; ++dt) {
      s = fmaf(acc[dt][q], as_v[dt], s);
      d = fmaf(acc[dt][q], ad_v[dt], d);
    }
    sv[q] = s; dv[q] = d;
  }
#pragma unroll
  for (int mm = 8; mm >= 1; mm >>= 1) {
#pragma unroll
    for (int q = 0; q < 4; ++q) {
      sv[q] += __shfl_xor(sv[q], mm);
      dv[q] += __shfl_xor(dv[q], mm);
    }
  }
  if (rloc == 0) {
#pragma unroll
    for (int q = 0; q < 4; ++q) {
      const int i = i0 + g * 4 + q;
      s_src[(size_t)h * NN + i] = sv[q] * LOG2E;
      d_dst[(size_t)h * NN + i] = dv[q] * LOG2E;
    }
  }
}

// ---------------------------------------------------------------------------
// K3: masked rank-1 softmax via block-local E-tables + PV (bf16 MFMA),
// LDS-staged & double-buffered. Mask words read DIRECTLY from L2 with
// 1-tile-ahead prefetch (no mk LDS staging) -> LDS 40 KB. DEFAULT launch
// bounds (r16's min-waves=6 cap forced VGPR=40 -> scratch spills, 305 MB
// HBM writes; never cap registers below the live set).
// grid (16 i-blocks, 4 heads, 4 j-quarters), block 512 = 8 waves x 32 rows.
// ---------------------------------------------------------------------------
__global__ __launch_bounds__(512) void k3_attn(
    const u8* __restrict__ mask,
    const u16* __restrict__ WxT,
    const float* __restrict__ s_src, const float* __restrict__ d_dst,
    u16* __restrict__ Pp, float* __restrict__ Sp)
{
  const int bx = blockIdx.x;
  const int h = blockIdx.y;
  const int jq = blockIdx.z;
  const int t = threadIdx.x;
  const int wv = t >> 6;
  const int lane = t & 63;
  const int rloc = lane & 15;
  const int g = lane >> 4;
  const int i_base = bx * 256 + wv * 32;

  __shared__ u16 wt[2][64 * 128];   // [buf][row*128 + unit*8], XOR-swizzled
  __shared__ float el[1024 * 2];    // (E1,E2) interleaved, 8 KiB

  const float md = MDC;
  const float si0 = s_src[(size_t)h * NN + i_base + rloc];
  const float si1 = s_src[(size_t)h * NN + i_base + 16 + rloc];
  const float e00 = si0 + md, e01 = si1 + md;
  const float m0 = fmaxf(e00, NEG_SLOPE * e00);
  const float m1 = fmaxf(e01, NEG_SLOPE * e01);
  const float sa0 = si0 - m0, sb0 = fmaf(NEG_SLOPE, si0, -m0);
  const float sa1 = si1 - m1, sb1 = fmaf(NEG_SLOPE, si1, -m1);
  float c1_0, c2_0, c1_1, c2_1;
  asm("v_exp_f32 %0, %1" : "=v"(c1_0) : "v"(sa0));
  asm("v_exp_f32 %0, %1" : "=v"(c2_0) : "v"(sb0));
  asm("v_exp_f32 %0, %1" : "=v"(c1_1) : "v"(sa1));
  asm("v_exp_f32 %0, %1" : "=v"(c2_1) : "v"(sb1));

  const u16* wsrc = WxT + (size_t)(h * HD) * NN + jq * 1024;
  // per-row mask pointers (one 128B line per row per jq, L2-resident)
  const u8* mrow0 = mask + (size_t)(i_base + rloc) * (NN / 8) + jq * 128;
  const u8* mrow1 = mask + (size_t)(i_base + 16 + rloc) * (NN / 8) + jq * 128;

  const int r0 = t >> 4;
  const int un = t & 15;
  const int up = un ^ (r0 & 7);

  // ---- prologue: E-table gen + WxT tile 0 + mask tile 0 ----
#pragma unroll
  for (int p = 0; p < 2; ++p) {
    const int j = p * 512 + t;
    const float dj = d_dst[(size_t)h * NN + jq * 1024 + j];
    const float djs = dj * NEG_SLOPE;
    float e1, e2;
    asm("v_exp_f32 %0, %1" : "=v"(e1) : "v"(dj));    // 2^dj
    asm("v_exp_f32 %0, %1" : "=v"(e2) : "v"(djs));   // 2^(0.2 dj)
    el[j * 2] = e1;
    el[j * 2 + 1] = e2;
  }
  {
    const uint4 s0 = *reinterpret_cast<const uint4*>(wsrc + (size_t)r0 * NN + un * 8);
    const uint4 s1 = *reinterpret_cast<const uint4*>(wsrc + (size_t)(r0 + 32) * NN + un * 8);
    *reinterpret_cast<uint4*>(&wt[0][r0 * 128 + up * 8]) = s0;
    *reinterpret_cast<uint4*>(&wt[0][(r0 + 32) * 128 + up * 8]) = s1;
  }
  uint4 mq0 = *reinterpret_cast<const uint4*>(mrow0);
  uint4 mq1 = *reinterpret_cast<const uint4*>(mrow1);
  __syncthreads();

  f32x4 acc0[4] = {}, acc1[4] = {};
  f32x4 accs0 = {}, accs1 = {};
  short8 ones;
#pragma unroll
  for (int e = 0; e < 8; ++e) ones[e] = (short)0x3F80;

  int buf = 0;
  for (int tile = 0; tile < 8; ++tile) {
    uint4 n0, n1, mn0, mn1;
    const bool pf = (tile < 7);
    if (pf) {
      n0 = *reinterpret_cast<const uint4*>(
          wsrc + (size_t)r0 * NN + (tile + 1) * 128 + un * 8);
      n1 = *reinterpret_cast<const uint4*>(
          wsrc + (size_t)(r0 + 32) * NN + (tile + 1) * 128 + un * 8);
      mn0 = *reinterpret_cast<const uint4*>(mrow0 + (tile + 1) * 16);
      mn1 = *reinterpret_cast<const uint4*>(mrow1 + (tile + 1) * 16);
    }

#pragma unroll
    for (int ks = 0; ks < 4; ++ks) {
      short8 bfr[4];
#pragma unroll
      for (int dt = 0; dt < 4; ++dt) {
        const int row = dt * 16 + rloc;
        const int unit = (ks * 4 + g) ^ (row & 7);
        bfr[dt] = *reinterpret_cast<const short8*>(&wt[buf][row * 128 + unit * 8]);
      }
      const int jloc = tile * 128 + ks * 32 + g * 8;
      const float* eb = &el[2 * jloc];
      const float4 Ea = *reinterpret_cast<const float4*>(eb);
      const float4 Eb = *reinterpret_cast<const float4*>(eb + 4);
      const float4 Ec = *reinterpret_cast<const float4*>(eb + 8);
      const float4 Ed = *reinterpret_cast<const float4*>(eb + 12);
      const float E1v[8] = {Ea.x, Ea.z, Eb.x, Eb.z, Ec.x, Ec.z, Ed.x, Ed.z};
      const float E2v[8] = {Ea.y, Ea.w, Eb.y, Eb.w, Ec.y, Ec.w, Ed.y, Ed.w};
      const u32 mw0 = (ks == 0) ? mq0.x : (ks == 1) ? mq0.y : (ks == 2) ? mq0.z : mq0.w;
      const u32 mw1 = (ks == 0) ? mq1.x : (ks == 1) ? mq1.y : (ks == 2) ? mq1.z : mq1.w;
      const u32 mb0 = (mw0 >> (g * 8)) & 0xffu;
      const u32 mb1 = (mw1 >> (g * 8)) & 0xffu;
      short8 af0, af1;
#pragma unroll
      for (int e = 0; e < 8; ++e) {
        float p0 = fmaxf(c1_0 * E1v[e], c2_0 * E2v[e]);
        float p1 = fmaxf(c1_1 * E1v[e], c2_1 * E2v[e]);
        p0 = (mb0 & (1u << e)) ? p0 : 0.f;
        p1 = (mb1 & (1u << e)) ? p1 : 0.f;
        __hip_bfloat16 b0 = __float2bfloat16(p0);
        __hip_bfloat16 b1 = __float2bfloat16(p1);
        af0[e] = *reinterpret_cast<const short*>(&b0);
        af1[e] = *reinterpret_cast<const short*>(&b1);
      }
#pragma unroll
      for (int dt = 0; dt < 4; ++dt) {
        acc0[dt] = __builtin_amdgcn_mfma_f32_16x16x32_bf16(af0, bfr[dt], acc0[dt], 0, 0, 0);
        acc1[dt] = __builtin_amdgcn_mfma_f32_16x16x32_bf16(af1, bfr[dt], acc1[dt], 0, 0, 0);
      }
      accs0 = __builtin_amdgcn_mfma_f32_16x16x32_bf16(af0, ones, accs0, 0, 0, 0);
      accs1 = __builtin_amdgcn_mfma_f32_16x16x32_bf16(af1, ones, accs1, 0, 0, 0);
    }

    if (pf) {
      *reinterpret_cast<uint4*>(&wt[buf ^ 1][r0 * 128 + up * 8]) = n0;
      *reinterpret_cast<uint4*>(&wt[buf ^ 1][(r0 + 32) * 128 + up * 8]) = n1;
      mq0 = mn0;
      mq1 = mn1;
    }
    __syncthreads();
    buf ^= 1;
  }

  u16* Pb = Pp + (size_t)jq * NN * OUT_DIM;
#pragma unroll
  for (int dt = 0; dt < 4; ++dt)
#pragma unroll
    for (int q = 0; q < 4; ++q) {
      __hip_bfloat16 v0 = __float2bfloat16(acc0[dt][q]);
      __hip_bfloat16 v1 = __float2bfloat16(acc1[dt][q]);
      Pb[(size_t)(i_base + g * 4 + q) * OUT_DIM + h * HD + dt * 16 + rloc] =
          *reinterpret_cast<const u16*>(&v0);
      Pb[(size_t)(i_base + 16 + g * 4 + q) * OUT_DIM + h * HD + dt * 16 + rloc] =
          *reinterpret_cast<const u16*>(&v1);
    }
  if (rloc == 0) {
    *reinterpret_cast<f32x4*>(&Sp[((size_t)jq * NH + h) * NN + i_base + g * 4]) = accs0;
    *reinterpret_cast<f32x4*>(&Sp[((size_t)jq * NH + h) * NN + i_base + 16 + g * 4]) = accs1;
  }
}

// ---------------------------------------------------------------------------
// K4: merge 4 j-quarter partials, normalize, ELU, LayerNorm, store.
// [round-7 verified]
// ---------------------------------------------------------------------------
__global__ __launch_bounds__(256) void k4_final(
    const u16* __restrict__ Pp, const float* __restrict__ Sp,
    const float* __restrict__ gamma, const float* __restrict__ beta,
    float* __restrict__ out)
{
  const int i0 = blockIdx.x * 16;
  const int t = threadIdx.x;
  const int wv = t >> 6;
  const int lane = t & 63;
  const int c0 = lane * 4;
  const int h = lane >> 4;

  const float4 gm = *reinterpret_cast<const float4*>(gamma + c0);
  const float4 bt = *reinterpret_cast<const float4*>(beta + c0);

  for (int rr = 0; rr < 4; ++rr) {
    const int i = i0 + wv * 4 + rr;
    float v[4] = {0.f, 0.f, 0.f, 0.f};
    float denom = 0.f;
#pragma unroll
    for (int q = 0; q < 4; ++q) {
      const ushort4 pv = *reinterpret_cast<const ushort4*>(
          Pp + (size_t)q * NN * OUT_DIM + (size_t)i * OUT_DIM + c0);
      v[0] += __uint_as_float((u32)pv.x << 16);
      v[1] += __uint_as_float((u32)pv.y << 16);
      v[2] += __uint_as_float((u32)pv.z << 16);
      v[3] += __uint_as_float((u32)pv.w << 16);
      denom += Sp[((size_t)q * NH + h) * NN + i];
    }
    const float inv = 1.f / denom;
    float sum = 0.f, sq = 0.f;
#pragma unroll
    for (int q2 = 0; q2 < 4; ++q2) {
      float xx = v[q2] * inv;
      xx = (xx > 0.f) ? xx : expm1f(xx);
      v[q2] = xx;
      sum += xx;
      sq += xx * xx;
    }
#pragma unroll
    for (int mm = 32; mm >= 1; mm >>= 1) {
      sum += __shfl_xor(sum, mm);
      sq += __shfl_xor(sq, mm);
    }
    const float mu = sum * (1.f / OUT_DIM);
    const float var = sq * (1.f / OUT_DIM) - mu * mu;
    const float rs = rsqrtf(var + LN_EPS);
    float4 o;
    o.x = (v[0] - mu) * rs * gm.x + bt.x;
    o.y = (v[1] - mu) * rs * gm.y + bt.y;
    o.z = (v[2] - mu) * rs * gm.z + bt.z;
    o.w = (v[3] - mu) * rs * gm.w + bt.w;
    *reinterpret_cast<float4*>(out + (size_t)i * OUT_DIM + c0) = o;
  }
}

extern "C" void kernel_launch(void* const* d_in, const int* in_sizes, int n_in,
                              void* d_out, int out_size, void* d_ws, size_t ws_size,
                              hipStream_t stream) {
  const float* x = (const float*)d_in[0];
  const int* adj = (const int*)d_in[1];
  const float* W = (const float*)d_in[2];
  const float* a = (const float*)d_in[3];
  const float* gamma = (const float*)d_in[4];
  const float* beta = (const float*)d_in[5];
  float* out = (float*)d_out;

  char* ws = (char*)d_ws;
  size_t off = 0;
  u16* WxT = (u16*)(ws + off);        off += (size_t)NH * HD * NN * 2;          // 2 MiB
  float* s_src = (float*)(ws + off);  off += (size_t)NH * NN * 4;               // 64 KiB
  float* d_dst = (float*)(ws + off);  off += (size_t)NH * NN * 4;               // 64 KiB
  u8* mask = (u8*)(ws + off);         off += (size_t)NN * (NN / 8);             // 2 MiB
  u16* Pp = (u16*)(ws + off);         off += (size_t)4 * NN * OUT_DIM * 2;      // 8 MiB (bf16)
  float* Sp = (float*)(ws + off);     off += (size_t)4 * NH * NN * 4;           // 256 KiB
  u16* Wt = (u16*)(ws + off);         off += (size_t)NH * HD * IN_DIM * 2;      // 256 KiB

  k0_wt<<<dim3(128), dim3(1024), 0, stream>>>(W, Wt);
  k1_proj<<<dim3(256), dim3(512), 0, stream>>>(x, Wt, a, adj, WxT, s_src,
                                               d_dst, mask);
  k3_attn<<<dim3(16, NH, 4), dim3(512), 0, stream>>>(mask, WxT, s_src, d_dst,
                                                     Pp, Sp);
  k4_final<<<dim3(256), dim3(256), 0, stream>>>(Pp, Sp, gamma, beta, out);
}

// Round 18
// 56.012 us; speedup vs baseline: 2.5028x; 1.0619x over previous
//
#include <hip/hip_runtime.h>
#include <hip/hip_bf16.h>

#define NN 4096
#define IN_DIM 512
#define OUT_DIM 256
#define NH 4
#define HD 64
#define NEG_SLOPE 0.2f
#define LN_EPS 1e-5f
#define LOG2E 1.4426950408889634f
#define MDC 8.0f   // constant softmax stabilizer (log2 domain); valid upper bound

typedef __attribute__((ext_vector_type(8))) short short8;
typedef __attribute__((ext_vector_type(4))) float f32x4;
typedef unsigned short u16;
typedef unsigned int u32;
typedef unsigned char u8;

// ---------------------------------------------------------------------------
// K0: transpose W [H][K][D] f32 -> Wt [h*64+d][512] bf16 (1 elem/thread).
// ---------------------------------------------------------------------------
__global__ __launch_bounds__(1024) void k0_wt(
    const float* __restrict__ W, u16* __restrict__ Wt)
{
  const int n = blockIdx.x * 1024 + threadIdx.x;   // n = h*2^15 + k*2^6 + d
  const int d = n & 63;
  const int k = (n >> 6) & 511;
  const int h = n >> 15;
  __hip_bfloat16 bv = __float2bfloat16(W[n]);
  Wt[(size_t)(h * HD + d) * IN_DIM + k] = *reinterpret_cast<const u16*>(&bv);
}

// ---------------------------------------------------------------------------
// K1: MFMA projection + adj->mask pack via WAVE SPECIALIZATION.
// [round-15 verified] grid 256, block 512 = 8 waves: waves 0-3 MFMA+scores,
// waves 4-7 streaming pack.
// ---------------------------------------------------------------------------
__global__ __launch_bounds__(512) void k1_proj(
    const float* __restrict__ x, const u16* __restrict__ Wt,
    const float* __restrict__ a, const int* __restrict__ adj,
    u16* __restrict__ WxT,
    float* __restrict__ s_src,
    float* __restrict__ d_dst,
    u8* __restrict__ mask)
{
  const int i0 = blockIdx.x * 16;
  const int t = threadIdx.x;
  const int wv = t >> 6;
  const int lane = t & 63;
  const int rloc = lane & 15;
  const int g = lane >> 4;

  __shared__ u16 xl[16 * 512];   // [row][unit*8], units XOR-swizzled by row&7

  // ---- stage x tile: 1024 (row,unit) pairs over 512 threads x 2 passes ----
#pragma unroll
  for (int p = 0; p < 2; ++p) {
    const int n = p * 512 + t;
    const int r = n >> 6;
    const int u = n & 63;
    const float* xr = x + (size_t)(i0 + r) * IN_DIM + u * 8;
    const float4 lo = *reinterpret_cast<const float4*>(xr);
    const float4 hi = *reinterpret_cast<const float4*>(xr + 4);
    const float fv[8] = {lo.x, lo.y, lo.z, lo.w, hi.x, hi.y, hi.z, hi.w};
    u16 us[8];
#pragma unroll
    for (int e = 0; e < 8; ++e) {
      __hip_bfloat16 bv = __float2bfloat16(fv[e]);
      us[e] = *reinterpret_cast<const u16*>(&bv);
    }
    const int phys = (u & 56) | ((u & 7) ^ (r & 7));
    uint4 pk;
    pk.x = (u32)us[0] | ((u32)us[1] << 16);
    pk.y = (u32)us[2] | ((u32)us[3] << 16);
    pk.z = (u32)us[4] | ((u32)us[5] << 16);
    pk.w = (u32)us[6] | ((u32)us[7] << 16);
    *reinterpret_cast<uint4*>(&xl[r * 512 + phys * 8]) = pk;
  }
  __syncthreads();

  if (wv >= 4) {
    // ---- pack waves: rows i0..i0+15, thread t2 covers cols [t2*16, +16) ----
    const int t2 = t - 256;
    const int j0 = t2 * 16;
#pragma unroll
    for (int rr = 0; rr < 16; ++rr) {
      const int row = i0 + rr;
      const int* ap = adj + (size_t)row * NN + j0;
      u32 bb = 0;
#pragma unroll
      for (int q = 0; q < 4; ++q) {
        const int4 v = *reinterpret_cast<const int4*>(ap + q * 4);
        const int vj = j0 + q * 4;
        if ((v.x > 0) || (row == vj))     bb |= 1u << (q * 4);
        if ((v.y > 0) || (row == vj + 1)) bb |= 1u << (q * 4 + 1);
        if ((v.z > 0) || (row == vj + 2)) bb |= 1u << (q * 4 + 2);
        if ((v.w > 0) || (row == vj + 3)) bb |= 1u << (q * 4 + 3);
      }
      *reinterpret_cast<u16*>(mask + (size_t)row * (NN / 8) + t2 * 2) = (u16)bb;
    }
    return;
  }

  // ---- compute waves: round-7 verified MFMA + scores (wave = head) ----
  const int h = wv;
  f32x4 acc[4] = {};
  const u16* wb = Wt + (size_t)(h * HD + rloc) * IN_DIM;
#pragma unroll
  for (int ks = 0; ks < 16; ++ks) {
    const int u = ks * 4 + g;
    const int phys = (u & 56) | ((u & 7) ^ (rloc & 7));
    const short8 af = *reinterpret_cast<const short8*>(&xl[rloc * 512 + phys * 8]);
#pragma unroll
    for (int dt = 0; dt < 4; ++dt) {
      const short8 bf = *reinterpret_cast<const short8*>(
          wb + (size_t)dt * 16 * IN_DIM + ks * 32 + g * 8);
      acc[dt] = __builtin_amdgcn_mfma_f32_16x16x32_bf16(af, bf, acc[dt], 0, 0, 0);
    }
  }

  // ---- epilogue: direct WxT store + scores ----
#pragma unroll
  for (int dt = 0; dt < 4; ++dt) {
    u16 us[4];
#pragma unroll
    for (int q = 0; q < 4; ++q) {
      __hip_bfloat16 bv = __float2bfloat16(acc[dt][q]);
      us[q] = *reinterpret_cast<const u16*>(&bv);
    }
    ushort4 pk = {us[0], us[1], us[2], us[3]};
    *reinterpret_cast<ushort4*>(
        WxT + (size_t)(h * HD + dt * 16 + rloc) * NN + i0 + g * 4) = pk;
  }

  float as_v[4], ad_v[4];
#pragma unroll
  for (int dt = 0; dt < 4; ++dt) {
    as_v[dt] = a[(size_t)h * 2 * HD + dt * 16 + rloc];
    ad_v[dt] = a[(size_t)h * 2 * HD + HD + dt * 16 + rloc];
  }
  float sv[4], dv[4];
#pragma unroll
  for (int q = 0; q < 4; ++q) {
    float s = 0.f, d = 0.f;
#pragma unroll
    for (int dt = 0; dt < 4; ++dt) {
      s = fmaf(acc[dt][q], as_v[dt], s);
      d = fmaf(acc[dt][q], ad_v[dt], d);
    }
    sv[q] = s; dv[q] = d;
  }
#pragma unroll
  for (int mm = 8; mm >= 1; mm >>= 1) {
#pragma unroll
    for (int q = 0; q < 4; ++q) {
      sv[q] += __shfl_xor(sv[q], mm);
      dv[q] += __shfl_xor(dv[q], mm);
    }
  }
  if (rloc == 0) {
#pragma unroll
    for (int q = 0; q < 4; ++q) {
      const int i = i0 + g * 4 + q;
      s_src[(size_t)h * NN + i] = sv[q] * LOG2E;
      d_dst[(size_t)h * NN + i] = dv[q] * LOG2E;
    }
  }
}

// ---------------------------------------------------------------------------
// K3: masked rank-1 softmax via block-local E-tables (LDS) + PV (bf16 MFMA),
// LDS-staged & double-buffered [round-15 verified base, 55.7us]. NEW: odd
// waves rotate the ks order by 2 (phase stagger) so half the waves are in the
// VALU-heavy p-build phase while the other half issue ds_read/MFMA - breaks
// the barrier-induced lockstep phase collision. Pure reorder of commutative
// accumulation: bit-identical result.
// grid (16 i-blocks, 4 heads, 4 j-quarters), block 512 = 8 waves x 32 rows.
// ---------------------------------------------------------------------------
__global__ __launch_bounds__(512) void k3_attn(
    const u8* __restrict__ mask,
    const u16* __restrict__ WxT,
    const float* __restrict__ s_src, const float* __restrict__ d_dst,
    u16* __restrict__ Pp, float* __restrict__ Sp)
{
  const int bx = blockIdx.x;
  const int h = blockIdx.y;
  const int jq = blockIdx.z;
  const int t = threadIdx.x;
  const int wv = t >> 6;
  const int lane = t & 63;
  const int rloc = lane & 15;
  const int g = lane >> 4;
  const int i_base = bx * 256 + wv * 32;
  const int ksrot = (wv & 1) * 2;   // phase stagger for odd waves

  __shared__ u16 wt[2][64 * 128];   // [buf][row*128 + unit*8], XOR-swizzled
  __shared__ u32 mk[256 * 36];      // [row][36 words] (32 used, pad 4)
  __shared__ float el[1024 * 2];    // (E1,E2) interleaved, 8 KiB

  const float md = MDC;
  const float si0 = s_src[(size_t)h * NN + i_base + rloc];
  const float si1 = s_src[(size_t)h * NN + i_base + 16 + rloc];
  const float e00 = si0 + md, e01 = si1 + md;
  const float m0 = fmaxf(e00, NEG_SLOPE * e00);
  const float m1 = fmaxf(e01, NEG_SLOPE * e01);
  const float sa0 = si0 - m0, sb0 = fmaf(NEG_SLOPE, si0, -m0);
  const float sa1 = si1 - m1, sb1 = fmaf(NEG_SLOPE, si1, -m1);
  float c1_0, c2_0, c1_1, c2_1;
  asm("v_exp_f32 %0, %1" : "=v"(c1_0) : "v"(sa0));
  asm("v_exp_f32 %0, %1" : "=v"(c2_0) : "v"(sb0));
  asm("v_exp_f32 %0, %1" : "=v"(c1_1) : "v"(sa1));
  asm("v_exp_f32 %0, %1" : "=v"(c2_1) : "v"(sb1));

  const u16* wsrc = WxT + (size_t)(h * HD) * NN + jq * 1024;

  const int r0 = t >> 4;
  const int un = t & 15;
  const int up = un ^ (r0 & 7);

  // ---- prologue: E-table gen + mask + WxT tile 0 ----
#pragma unroll
  for (int p = 0; p < 2; ++p) {
    const int j = p * 512 + t;
    const float dj = d_dst[(size_t)h * NN + jq * 1024 + j];
    const float djs = dj * NEG_SLOPE;
    float e1, e2;
    asm("v_exp_f32 %0, %1" : "=v"(e1) : "v"(dj));    // 2^dj
    asm("v_exp_f32 %0, %1" : "=v"(e2) : "v"(djs));   // 2^(0.2 dj)
    el[j * 2] = e1;
    el[j * 2 + 1] = e2;
  }
#pragma unroll
  for (int k = 0; k < 4; ++k) {
    const int n = k * 512 + t;
    const int row = n >> 3;
    const int quad = n & 7;
    const uint4 mv = *reinterpret_cast<const uint4*>(
        mask + ((size_t)(bx * 256 + row) * (NN / 8)) + jq * 128 + quad * 16);
    *reinterpret_cast<uint4*>(&mk[row * 36 + quad * 4]) = mv;
  }
  {
    const uint4 s0 = *reinterpret_cast<const uint4*>(wsrc + (size_t)r0 * NN + un * 8);
    const uint4 s1 = *reinterpret_cast<const uint4*>(wsrc + (size_t)(r0 + 32) * NN + un * 8);
    *reinterpret_cast<uint4*>(&wt[0][r0 * 128 + up * 8]) = s0;
    *reinterpret_cast<uint4*>(&wt[0][(r0 + 32) * 128 + up * 8]) = s1;
  }
  __syncthreads();

  f32x4 acc0[4] = {}, acc1[4] = {};
  f32x4 accs0 = {}, accs1 = {};
  short8 ones;
#pragma unroll
  for (int e = 0; e < 8; ++e) ones[e] = (short)0x3F80;

  int buf = 0;
  for (int tile = 0; tile < 8; ++tile) {
    uint4 n0, n1;
    const bool pf = (tile < 7);
    if (pf) {
      n0 = *reinterpret_cast<const uint4*>(
          wsrc + (size_t)r0 * NN + (tile + 1) * 128 + un * 8);
      n1 = *reinterpret_cast<const uint4*>(
          wsrc + (size_t)(r0 + 32) * NN + (tile + 1) * 128 + un * 8);
    }

    const uint4 mq0 = *reinterpret_cast<const uint4*>(
        &mk[(wv * 32 + rloc) * 36 + tile * 4]);
    const uint4 mq1 = *reinterpret_cast<const uint4*>(
        &mk[(wv * 32 + 16 + rloc) * 36 + tile * 4]);
#pragma unroll
    for (int ks0 = 0; ks0 < 4; ++ks0) {
      const int ks = (ks0 + ksrot) & 3;   // odd waves run 2,3,0,1
      short8 bfr[4];
#pragma unroll
      for (int dt = 0; dt < 4; ++dt) {
        const int row = dt * 16 + rloc;
        const int unit = (ks * 4 + g) ^ (row & 7);
        bfr[dt] = *reinterpret_cast<const short8*>(&wt[buf][row * 128 + unit * 8]);
      }
      const int jloc = tile * 128 + ks * 32 + g * 8;
      const float* eb = &el[2 * jloc];
      const float4 Ea = *reinterpret_cast<const float4*>(eb);
      const float4 Eb = *reinterpret_cast<const float4*>(eb + 4);
      const float4 Ec = *reinterpret_cast<const float4*>(eb + 8);
      const float4 Ed = *reinterpret_cast<const float4*>(eb + 12);
      const float E1v[8] = {Ea.x, Ea.z, Eb.x, Eb.z, Ec.x, Ec.z, Ed.x, Ed.z};
      const float E2v[8] = {Ea.y, Ea.w, Eb.y, Eb.w, Ec.y, Ec.w, Ed.y, Ed.w};
      const u32 mw0 = (ks == 0) ? mq0.x : (ks == 1) ? mq0.y : (ks == 2) ? mq0.z : mq0.w;
      const u32 mw1 = (ks == 0) ? mq1.x : (ks == 1) ? mq1.y : (ks == 2) ? mq1.z : mq1.w;
      const u32 mb0 = (mw0 >> (g * 8)) & 0xffu;
      const u32 mb1 = (mw1 >> (g * 8)) & 0xffu;
      short8 af0, af1;
#pragma unroll
      for (int e = 0; e < 8; ++e) {
        float p0 = fmaxf(c1_0 * E1v[e], c2_0 * E2v[e]);
        float p1 = fmaxf(c1_1 * E1v[e], c2_1 * E2v[e]);
        p0 = (mb0 & (1u << e)) ? p0 : 0.f;
        p1 = (mb1 & (1u << e)) ? p1 : 0.f;
        __hip_bfloat16 b0 = __float2bfloat16(p0);
        __hip_bfloat16 b1 = __float2bfloat16(p1);
        af0[e] = *reinterpret_cast<const short*>(&b0);
        af1[e] = *reinterpret_cast<const short*>(&b1);
      }
#pragma unroll
      for (int dt = 0; dt < 4; ++dt) {
        acc0[dt] = __builtin_amdgcn_mfma_f32_16x16x32_bf16(af0, bfr[dt], acc0[dt], 0, 0, 0);
        acc1[dt] = __builtin_amdgcn_mfma_f32_16x16x32_bf16(af1, bfr[dt], acc1[dt], 0, 0, 0);
      }
      accs0 = __builtin_amdgcn_mfma_f32_16x16x32_bf16(af0, ones, accs0, 0, 0, 0);
      accs1 = __builtin_amdgcn_mfma_f32_16x16x32_bf16(af1, ones, accs1, 0, 0, 0);
    }

    if (pf) {
      *reinterpret_cast<uint4*>(&wt[buf ^ 1][r0 * 128 + up * 8]) = n0;
      *reinterpret_cast<uint4*>(&wt[buf ^ 1][(r0 + 32) * 128 + up * 8]) = n1;
    }
    __syncthreads();
    buf ^= 1;
  }

  u16* Pb = Pp + (size_t)jq * NN * OUT_DIM;
#pragma unroll
  for (int dt = 0; dt < 4; ++dt)
#pragma unroll
    for (int q = 0; q < 4; ++q) {
      __hip_bfloat16 v0 = __float2bfloat16(acc0[dt][q]);
      __hip_bfloat16 v1 = __float2bfloat16(acc1[dt][q]);
      Pb[(size_t)(i_base + g * 4 + q) * OUT_DIM + h * HD + dt * 16 + rloc] =
          *reinterpret_cast<const u16*>(&v0);
      Pb[(size_t)(i_base + 16 + g * 4 + q) * OUT_DIM + h * HD + dt * 16 + rloc] =
          *reinterpret_cast<const u16*>(&v1);
    }
  if (rloc == 0) {
    *reinterpret_cast<f32x4*>(&Sp[((size_t)jq * NH + h) * NN + i_base + g * 4]) = accs0;
    *reinterpret_cast<f32x4*>(&Sp[((size_t)jq * NH + h) * NN + i_base + 16 + g * 4]) = accs1;
  }
}

// ---------------------------------------------------------------------------
// K4: merge 4 j-quarter partials, normalize, ELU, LayerNorm, store.
// [round-7 verified]
// ---------------------------------------------------------------------------
__global__ __launch_bounds__(256) void k4_final(
    const u16* __restrict__ Pp, const float* __restrict__ Sp,
    const float* __restrict__ gamma, const float* __restrict__ beta,
    float* __restrict__ out)
{
  const int i0 = blockIdx.x * 16;
  const int t = threadIdx.x;
  const int wv = t >> 6;
  const int lane = t & 63;
  const int c0 = lane * 4;
  const int h = lane >> 4;

  const float4 gm = *reinterpret_cast<const float4*>(gamma + c0);
  const float4 bt = *reinterpret_cast<const float4*>(beta + c0);

  for (int rr = 0; rr < 4; ++rr) {
    const int i = i0 + wv * 4 + rr;
    float v[4] = {0.f, 0.f, 0.f, 0.f};
    float denom = 0.f;
#pragma unroll
    for (int q = 0; q < 4; ++q) {
      const ushort4 pv = *reinterpret_cast<const ushort4*>(
          Pp + (size_t)q * NN * OUT_DIM + (size_t)i * OUT_DIM + c0);
      v[0] += __uint_as_float((u32)pv.x << 16);
      v[1] += __uint_as_float((u32)pv.y << 16);
      v[2] += __uint_as_float((u32)pv.z << 16);
      v[3] += __uint_as_float((u32)pv.w << 16);
      denom += Sp[((size_t)q * NH + h) * NN + i];
    }
    const float inv = 1.f / denom;
    float sum = 0.f, sq = 0.f;
#pragma unroll
    for (int q2 = 0; q2 < 4; ++q2) {
      float xx = v[q2] * inv;
      xx = (xx > 0.f) ? xx : expm1f(xx);
      v[q2] = xx;
      sum += xx;
      sq += xx * xx;
    }
#pragma unroll
    for (int mm = 32; mm >= 1; mm >>= 1) {
      sum += __shfl_xor(sum, mm);
      sq += __shfl_xor(sq, mm);
    }
    const float mu = sum * (1.f / OUT_DIM);
    const float var = sq * (1.f / OUT_DIM) - mu * mu;
    const float rs = rsqrtf(var + LN_EPS);
    float4 o;
    o.x = (v[0] - mu) * rs * gm.x + bt.x;
    o.y = (v[1] - mu) * rs * gm.y + bt.y;
    o.z = (v[2] - mu) * rs * gm.z + bt.z;
    o.w = (v[3] - mu) * rs * gm.w + bt.w;
    *reinterpret_cast<float4*>(out + (size_t)i * OUT_DIM + c0) = o;
  }
}

extern "C" void kernel_launch(void* const* d_in, const int* in_sizes, int n_in,
                              void* d_out, int out_size, void* d_ws, size_t ws_size,
                              hipStream_t stream) {
  const float* x = (const float*)d_in[0];
  const int* adj = (const int*)d_in[1];
  const float* W = (const float*)d_in[2];
  const float* a = (const float*)d_in[3];
  const float* gamma = (const float*)d_in[4];
  const float* beta = (const float*)d_in[5];
  float* out = (float*)d_out;

  char* ws = (char*)d_ws;
  size_t off = 0;
  u16* WxT = (u16*)(ws + off);        off += (size_t)NH * HD * NN * 2;          // 2 MiB
  float* s_src = (float*)(ws + off);  off += (size_t)NH * NN * 4;               // 64 KiB
  float* d_dst = (float*)(ws + off);  off += (size_t)NH * NN * 4;               // 64 KiB
  u8* mask = (u8*)(ws + off);         off += (size_t)NN * (NN / 8);             // 2 MiB
  u16* Pp = (u16*)(ws + off);         off += (size_t)4 * NN * OUT_DIM * 2;      // 8 MiB (bf16)
  float* Sp = (float*)(ws + off);     off += (size_t)4 * NH * NN * 4;           // 256 KiB
  u16* Wt = (u16*)(ws + off);         off += (size_t)NH * HD * IN_DIM * 2;      // 256 KiB

  k0_wt<<<dim3(128), dim3(1024), 0, stream>>>(W, Wt);
  k1_proj<<<dim3(256), dim3(512), 0, stream>>>(x, Wt, a, adj, WxT, s_src,
                                               d_dst, mask);
  k3_attn<<<dim3(16, NH, 4), dim3(512), 0, stream>>>(mask, WxT, s_src, d_dst,
                                                     Pp, Sp);
  k4_final<<<dim3(256), dim3(256), 0, stream>>>(Pp, Sp, gamma, beta, out);
}

// Round 19
// 54.351 us; speedup vs baseline: 2.5793x; 1.0306x over previous
//
#include <hip/hip_runtime.h>
#include <hip/hip_bf16.h>

#define NN 4096
#define IN_DIM 512
#define OUT_DIM 256
#define NH 4
#define HD 64
#define NEG_SLOPE 0.2f
#define LN_EPS 1e-5f
#define LOG2E 1.4426950408889634f
#define MDC 8.0f   // constant softmax stabilizer (log2 domain); valid upper bound

typedef __attribute__((ext_vector_type(8))) short short8;
typedef __attribute__((ext_vector_type(4))) float f32x4;
typedef unsigned short u16;
typedef unsigned int u32;
typedef unsigned char u8;

// ---------------------------------------------------------------------------
// K0: transpose W [H][K][D] f32 -> Wt [h*64+d][512] bf16 (1 elem/thread).
// ---------------------------------------------------------------------------
__global__ __launch_bounds__(1024) void k0_wt(
    const float* __restrict__ W, u16* __restrict__ Wt)
{
  const int n = blockIdx.x * 1024 + threadIdx.x;   // n = h*2^15 + k*2^6 + d
  const int d = n & 63;
  const int k = (n >> 6) & 511;
  const int h = n >> 15;
  __hip_bfloat16 bv = __float2bfloat16(W[n]);
  Wt[(size_t)(h * HD + d) * IN_DIM + k] = *reinterpret_cast<const u16*>(&bv);
}

// ---------------------------------------------------------------------------
// K1: MFMA projection with ALL-LDS operands + adj->mask pack via wave
// specialization. grid 256 = (64-row i-tile = bx>>2, head h = bx&3),
// block 512 = 8 waves: waves 0-3 compute (16 rows each, head h, A and B
// both from LDS); waves 4-7 pack rows i0+h*16..+16 (1x coverage across the
// 4 head-blocks of each tile). LDS = x tile 64 KB + Wt head-slice 64 KB.
// r9's all-LDS loop (verified) at r15's occupancy (pack waves hide latency).
// ---------------------------------------------------------------------------
__global__ __launch_bounds__(512) void k1_proj(
    const float* __restrict__ x, const u16* __restrict__ Wt,
    const float* __restrict__ a, const int* __restrict__ adj,
    u16* __restrict__ WxT,
    float* __restrict__ s_src,
    float* __restrict__ d_dst,
    u8* __restrict__ mask)
{
  const int h = blockIdx.x & 3;
  const int i0 = (blockIdx.x >> 2) * 64;
  const int t = threadIdx.x;
  const int wv = t >> 6;
  const int lane = t & 63;
  const int rloc = lane & 15;
  const int g = lane >> 4;

  __shared__ u16 xl[64 * 512];   // 64 KiB: x rows i0..i0+63, swizzled units
  __shared__ u16 wl[64 * 512];   // 64 KiB: Wt rows h*64..h*64+63, swizzled

  // ---- stage x tile + Wt head slice: 4096 (row,unit) pairs x 8 passes ----
#pragma unroll
  for (int p = 0; p < 8; ++p) {
    const int n = p * 512 + t;
    const int r = n >> 6;
    const int u = n & 63;
    const int phys = (u & 56) | ((u & 7) ^ (r & 7));
    // x row (f32 -> bf16)
    const float* xr = x + (size_t)(i0 + r) * IN_DIM + u * 8;
    const float4 lo = *reinterpret_cast<const float4*>(xr);
    const float4 hi = *reinterpret_cast<const float4*>(xr + 4);
    const float fv[8] = {lo.x, lo.y, lo.z, lo.w, hi.x, hi.y, hi.z, hi.w};
    u16 us[8];
#pragma unroll
    for (int e = 0; e < 8; ++e) {
      __hip_bfloat16 bv = __float2bfloat16(fv[e]);
      us[e] = *reinterpret_cast<const u16*>(&bv);
    }
    uint4 pk;
    pk.x = (u32)us[0] | ((u32)us[1] << 16);
    pk.y = (u32)us[2] | ((u32)us[3] << 16);
    pk.z = (u32)us[4] | ((u32)us[5] << 16);
    pk.w = (u32)us[6] | ((u32)us[7] << 16);
    *reinterpret_cast<uint4*>(&xl[r * 512 + phys * 8]) = pk;
    // Wt row (already bf16): plain copy
    const uint4 wsv = *reinterpret_cast<const uint4*>(
        Wt + (size_t)(h * HD + r) * IN_DIM + u * 8);
    *reinterpret_cast<uint4*>(&wl[r * 512 + phys * 8]) = wsv;
  }
  __syncthreads();

  if (wv >= 4) {
    // ---- pack waves: rows i0+h*16 .. +16, thread t2 covers cols [t2*16,+16)
    const int t2 = t - 256;
    const int j0 = t2 * 16;
    const int prow0 = i0 + h * 16;
#pragma unroll
    for (int rr = 0; rr < 16; ++rr) {
      const int row = prow0 + rr;
      const int* ap = adj + (size_t)row * NN + j0;
      u32 bb = 0;
#pragma unroll
      for (int q = 0; q < 4; ++q) {
        const int4 v = *reinterpret_cast<const int4*>(ap + q * 4);
        const int vj = j0 + q * 4;
        if ((v.x > 0) || (row == vj))     bb |= 1u << (q * 4);
        if ((v.y > 0) || (row == vj + 1)) bb |= 1u << (q * 4 + 1);
        if ((v.z > 0) || (row == vj + 2)) bb |= 1u << (q * 4 + 2);
        if ((v.w > 0) || (row == vj + 3)) bb |= 1u << (q * 4 + 3);
      }
      *reinterpret_cast<u16*>(mask + (size_t)row * (NN / 8) + t2 * 2) = (u16)bb;
    }
    return;
  }

  // ---- compute waves: rows rbase..rbase+16, all-LDS MFMA loop [r9 verified]
  const int rbase = wv * 16;
  f32x4 acc[4] = {};
#pragma unroll
  for (int ks = 0; ks < 16; ++ks) {
    const int u = ks * 4 + g;
    const int ar = rbase + rloc;
    const int aphys = (u & 56) | ((u & 7) ^ (ar & 7));
    const short8 af = *reinterpret_cast<const short8*>(&xl[ar * 512 + aphys * 8]);
#pragma unroll
    for (int dt = 0; dt < 4; ++dt) {
      const int br = dt * 16 + rloc;
      const int bphys = (u & 56) | ((u & 7) ^ (br & 7));
      const short8 bf = *reinterpret_cast<const short8*>(&wl[br * 512 + bphys * 8]);
      acc[dt] = __builtin_amdgcn_mfma_f32_16x16x32_bf16(af, bf, acc[dt], 0, 0, 0);
    }
  }

  // ---- epilogue: WxT store (acc[dt][q] = C[i=rbase+g*4+q][d=dt*16+rloc]) ----
#pragma unroll
  for (int dt = 0; dt < 4; ++dt) {
    u16 us[4];
#pragma unroll
    for (int q = 0; q < 4; ++q) {
      __hip_bfloat16 bv = __float2bfloat16(acc[dt][q]);
      us[q] = *reinterpret_cast<const u16*>(&bv);
    }
    ushort4 pk = {us[0], us[1], us[2], us[3]};
    *reinterpret_cast<ushort4*>(
        WxT + (size_t)(h * HD + dt * 16 + rloc) * NN + i0 + rbase + g * 4) = pk;
  }

  // ---- scores ----
  float as_v[4], ad_v[4];
#pragma unroll
  for (int dt = 0; dt < 4; ++dt) {
    as_v[dt] = a[(size_t)h * 2 * HD + dt * 16 + rloc];
    ad_v[dt] = a[(size_t)h * 2 * HD + HD + dt * 16 + rloc];
  }
  float sv[4], dv[4];
#pragma unroll
  for (int q = 0; q < 4; ++q) {
    float s = 0.f, d = 0.f;
#pragma unroll
    for (int dt = 0; dt < 4; ++dt) {
      s = fmaf(acc[dt][q], as_v[dt], s);
      d = fmaf(acc[dt][q], ad_v[dt], d);
    }
    sv[q] = s; dv[q] = d;
  }
#pragma unroll
  for (int mm = 8; mm >= 1; mm >>= 1) {
#pragma unroll
    for (int q = 0; q < 4; ++q) {
      sv[q] += __shfl_xor(sv[q], mm);
      dv[q] += __shfl_xor(dv[q], mm);
    }
  }
  if (rloc == 0) {
#pragma unroll
    for (int q = 0; q < 4; ++q) {
      const int i = i0 + rbase + g * 4 + q;
      s_src[(size_t)h * NN + i] = sv[q] * LOG2E;
      d_dst[(size_t)h * NN + i] = dv[q] * LOG2E;
    }
  }
}

// ---------------------------------------------------------------------------
// K3: masked rank-1 softmax via block-local E-tables (LDS) + PV (bf16 MFMA),
// LDS-staged & double-buffered [round-15 verified, best config].
// grid (16 i-blocks, 4 heads, 4 j-quarters), block 512 = 8 waves x 32 rows.
// ---------------------------------------------------------------------------
__global__ __launch_bounds__(512) void k3_attn(
    const u8* __restrict__ mask,
    const u16* __restrict__ WxT,
    const float* __restrict__ s_src, const float* __restrict__ d_dst,
    u16* __restrict__ Pp, float* __restrict__ Sp)
{
  const int bx = blockIdx.x;
  const int h = blockIdx.y;
  const int jq = blockIdx.z;
  const int t = threadIdx.x;
  const int wv = t >> 6;
  const int lane = t & 63;
  const int rloc = lane & 15;
  const int g = lane >> 4;
  const int i_base = bx * 256 + wv * 32;

  __shared__ u16 wt[2][64 * 128];   // [buf][row*128 + unit*8], XOR-swizzled
  __shared__ u32 mk[256 * 36];      // [row][36 words] (32 used, pad 4)
  __shared__ float el[1024 * 2];    // (E1,E2) interleaved, 8 KiB

  const float md = MDC;
  const float si0 = s_src[(size_t)h * NN + i_base + rloc];
  const float si1 = s_src[(size_t)h * NN + i_base + 16 + rloc];
  const float e00 = si0 + md, e01 = si1 + md;
  const float m0 = fmaxf(e00, NEG_SLOPE * e00);
  const float m1 = fmaxf(e01, NEG_SLOPE * e01);
  const float sa0 = si0 - m0, sb0 = fmaf(NEG_SLOPE, si0, -m0);
  const float sa1 = si1 - m1, sb1 = fmaf(NEG_SLOPE, si1, -m1);
  float c1_0, c2_0, c1_1, c2_1;
  asm("v_exp_f32 %0, %1" : "=v"(c1_0) : "v"(sa0));
  asm("v_exp_f32 %0, %1" : "=v"(c2_0) : "v"(sb0));
  asm("v_exp_f32 %0, %1" : "=v"(c1_1) : "v"(sa1));
  asm("v_exp_f32 %0, %1" : "=v"(c2_1) : "v"(sb1));

  const u16* wsrc = WxT + (size_t)(h * HD) * NN + jq * 1024;

  const int r0 = t >> 4;
  const int un = t & 15;
  const int up = un ^ (r0 & 7);

  // ---- prologue: E-table gen + mask + WxT tile 0 ----
#pragma unroll
  for (int p = 0; p < 2; ++p) {
    const int j = p * 512 + t;
    const float dj = d_dst[(size_t)h * NN + jq * 1024 + j];
    const float djs = dj * NEG_SLOPE;
    float e1, e2;
    asm("v_exp_f32 %0, %1" : "=v"(e1) : "v"(dj));    // 2^dj
    asm("v_exp_f32 %0, %1" : "=v"(e2) : "v"(djs));   // 2^(0.2 dj)
    el[j * 2] = e1;
    el[j * 2 + 1] = e2;
  }
#pragma unroll
  for (int k = 0; k < 4; ++k) {
    const int n = k * 512 + t;
    const int row = n >> 3;
    const int quad = n & 7;
    const uint4 mv = *reinterpret_cast<const uint4*>(
        mask + ((size_t)(bx * 256 + row) * (NN / 8)) + jq * 128 + quad * 16);
    *reinterpret_cast<uint4*>(&mk[row * 36 + quad * 4]) = mv;
  }
  {
    const uint4 s0 = *reinterpret_cast<const uint4*>(wsrc + (size_t)r0 * NN + un * 8);
    const uint4 s1 = *reinterpret_cast<const uint4*>(wsrc + (size_t)(r0 + 32) * NN + un * 8);
    *reinterpret_cast<uint4*>(&wt[0][r0 * 128 + up * 8]) = s0;
    *reinterpret_cast<uint4*>(&wt[0][(r0 + 32) * 128 + up * 8]) = s1;
  }
  __syncthreads();

  f32x4 acc0[4] = {}, acc1[4] = {};
  f32x4 accs0 = {}, accs1 = {};
  short8 ones;
#pragma unroll
  for (int e = 0; e < 8; ++e) ones[e] = (short)0x3F80;

  int buf = 0;
  for (int tile = 0; tile < 8; ++tile) {
    uint4 n0, n1;
    const bool pf = (tile < 7);
    if (pf) {
      n0 = *reinterpret_cast<const uint4*>(
          wsrc + (size_t)r0 * NN + (tile + 1) * 128 + un * 8);
      n1 = *reinterpret_cast<const uint4*>(
          wsrc + (size_t)(r0 + 32) * NN + (tile + 1) * 128 + un * 8);
    }

    const uint4 mq0 = *reinterpret_cast<const uint4*>(
        &mk[(wv * 32 + rloc) * 36 + tile * 4]);
    const uint4 mq1 = *reinterpret_cast<const uint4*>(
        &mk[(wv * 32 + 16 + rloc) * 36 + tile * 4]);
#pragma unroll
    for (int ks = 0; ks < 4; ++ks) {
      short8 bfr[4];
#pragma unroll
      for (int dt = 0; dt < 4; ++dt) {
        const int row = dt * 16 + rloc;
        const int unit = (ks * 4 + g) ^ (row & 7);
        bfr[dt] = *reinterpret_cast<const short8*>(&wt[buf][row * 128 + unit * 8]);
      }
      const int jloc = tile * 128 + ks * 32 + g * 8;
      const float* eb = &el[2 * jloc];
      const float4 Ea = *reinterpret_cast<const float4*>(eb);
      const float4 Eb = *reinterpret_cast<const float4*>(eb + 4);
      const float4 Ec = *reinterpret_cast<const float4*>(eb + 8);
      const float4 Ed = *reinterpret_cast<const float4*>(eb + 12);
      const float E1v[8] = {Ea.x, Ea.z, Eb.x, Eb.z, Ec.x, Ec.z, Ed.x, Ed.z};
      const float E2v[8] = {Ea.y, Ea.w, Eb.y, Eb.w, Ec.y, Ec.w, Ed.y, Ed.w};
      const u32 mw0 = (ks == 0) ? mq0.x : (ks == 1) ? mq0.y : (ks == 2) ? mq0.z : mq0.w;
      const u32 mw1 = (ks == 0) ? mq1.x : (ks == 1) ? mq1.y : (ks == 2) ? mq1.z : mq1.w;
      const u32 mb0 = (mw0 >> (g * 8)) & 0xffu;
      const u32 mb1 = (mw1 >> (g * 8)) & 0xffu;
      short8 af0, af1;
#pragma unroll
      for (int e = 0; e < 8; ++e) {
        float p0 = fmaxf(c1_0 * E1v[e], c2_0 * E2v[e]);
        float p1 = fmaxf(c1_1 * E1v[e], c2_1 * E2v[e]);
        p0 = (mb0 & (1u << e)) ? p0 : 0.f;
        p1 = (mb1 & (1u << e)) ? p1 : 0.f;
        __hip_bfloat16 b0 = __float2bfloat16(p0);
        __hip_bfloat16 b1 = __float2bfloat16(p1);
        af0[e] = *reinterpret_cast<const short*>(&b0);
        af1[e] = *reinterpret_cast<const short*>(&b1);
      }
#pragma unroll
      for (int dt = 0; dt < 4; ++dt) {
        acc0[dt] = __builtin_amdgcn_mfma_f32_16x16x32_bf16(af0, bfr[dt], acc0[dt], 0, 0, 0);
        acc1[dt] = __builtin_amdgcn_mfma_f32_16x16x32_bf16(af1, bfr[dt], acc1[dt], 0, 0, 0);
      }
      accs0 = __builtin_amdgcn_mfma_f32_16x16x32_bf16(af0, ones, accs0, 0, 0, 0);
      accs1 = __builtin_amdgcn_mfma_f32_16x16x32_bf16(af1, ones, accs1, 0, 0, 0);
    }

    if (pf) {
      *reinterpret_cast<uint4*>(&wt[buf ^ 1][r0 * 128 + up * 8]) = n0;
      *reinterpret_cast<uint4*>(&wt[buf ^ 1][(r0 + 32) * 128 + up * 8]) = n1;
    }
    __syncthreads();
    buf ^= 1;
  }

  u16* Pb = Pp + (size_t)jq * NN * OUT_DIM;
#pragma unroll
  for (int dt = 0; dt < 4; ++dt)
#pragma unroll
    for (int q = 0; q < 4; ++q) {
      __hip_bfloat16 v0 = __float2bfloat16(acc0[dt][q]);
      __hip_bfloat16 v1 = __float2bfloat16(acc1[dt][q]);
      Pb[(size_t)(i_base + g * 4 + q) * OUT_DIM + h * HD + dt * 16 + rloc] =
          *reinterpret_cast<const u16*>(&v0);
      Pb[(size_t)(i_base + 16 + g * 4 + q) * OUT_DIM + h * HD + dt * 16 + rloc] =
          *reinterpret_cast<const u16*>(&v1);
    }
  if (rloc == 0) {
    *reinterpret_cast<f32x4*>(&Sp[((size_t)jq * NH + h) * NN + i_base + g * 4]) = accs0;
    *reinterpret_cast<f32x4*>(&Sp[((size_t)jq * NH + h) * NN + i_base + 16 + g * 4]) = accs1;
  }
}

// ---------------------------------------------------------------------------
// K4: merge 4 j-quarter partials, normalize, ELU, LayerNorm, store.
// [round-7 verified]
// ---------------------------------------------------------------------------
__global__ __launch_bounds__(256) void k4_final(
    const u16* __restrict__ Pp, const float* __restrict__ Sp,
    const float* __restrict__ gamma, const float* __restrict__ beta,
    float* __restrict__ out)
{
  const int i0 = blockIdx.x * 16;
  const int t = threadIdx.x;
  const int wv = t >> 6;
  const int lane = t & 63;
  const int c0 = lane * 4;
  const int h = lane >> 4;

  const float4 gm = *reinterpret_cast<const float4*>(gamma + c0);
  const float4 bt = *reinterpret_cast<const float4*>(beta + c0);

  for (int rr = 0; rr < 4; ++rr) {
    const int i = i0 + wv * 4 + rr;
    float v[4] = {0.f, 0.f, 0.f, 0.f};
    float denom = 0.f;
#pragma unroll
    for (int q = 0; q < 4; ++q) {
      const ushort4 pv = *reinterpret_cast<const ushort4*>(
          Pp + (size_t)q * NN * OUT_DIM + (size_t)i * OUT_DIM + c0);
      v[0] += __uint_as_float((u32)pv.x << 16);
      v[1] += __uint_as_float((u32)pv.y << 16);
      v[2] += __uint_as_float((u32)pv.z << 16);
      v[3] += __uint_as_float((u32)pv.w << 16);
      denom += Sp[((size_t)q * NH + h) * NN + i];
    }
    const float inv = 1.f / denom;
    float sum = 0.f, sq = 0.f;
#pragma unroll
    for (int q2 = 0; q2 < 4; ++q2) {
      float xx = v[q2] * inv;
      xx = (xx > 0.f) ? xx : expm1f(xx);
      v[q2] = xx;
      sum += xx;
      sq += xx * xx;
    }
#pragma unroll
    for (int mm = 32; mm >= 1; mm >>= 1) {
      sum += __shfl_xor(sum, mm);
      sq += __shfl_xor(sq, mm);
    }
    const float mu = sum * (1.f / OUT_DIM);
    const float var = sq * (1.f / OUT_DIM) - mu * mu;
    const float rs = rsqrtf(var + LN_EPS);
    float4 o;
    o.x = (v[0] - mu) * rs * gm.x + bt.x;
    o.y = (v[1] - mu) * rs * gm.y + bt.y;
    o.z = (v[2] - mu) * rs * gm.z + bt.z;
    o.w = (v[3] - mu) * rs * gm.w + bt.w;
    *reinterpret_cast<float4*>(out + (size_t)i * OUT_DIM + c0) = o;
  }
}

extern "C" void kernel_launch(void* const* d_in, const int* in_sizes, int n_in,
                              void* d_out, int out_size, void* d_ws, size_t ws_size,
                              hipStream_t stream) {
  const float* x = (const float*)d_in[0];
  const int* adj = (const int*)d_in[1];
  const float* W = (const float*)d_in[2];
  const float* a = (const float*)d_in[3];
  const float* gamma = (const float*)d_in[4];
  const float* beta = (const float*)d_in[5];
  float* out = (float*)d_out;

  char* ws = (char*)d_ws;
  size_t off = 0;
  u16* WxT = (u16*)(ws + off);        off += (size_t)NH * HD * NN * 2;          // 2 MiB
  float* s_src = (float*)(ws + off);  off += (size_t)NH * NN * 4;               // 64 KiB
  float* d_dst = (float*)(ws + off);  off += (size_t)NH * NN * 4;               // 64 KiB
  u8* mask = (u8*)(ws + off);         off += (size_t)NN * (NN / 8);             // 2 MiB
  u16* Pp = (u16*)(ws + off);         off += (size_t)4 * NN * OUT_DIM * 2;      // 8 MiB (bf16)
  float* Sp = (float*)(ws + off);     off += (size_t)4 * NH * NN * 4;           // 256 KiB
  u16* Wt = (u16*)(ws + off);         off += (size_t)NH * HD * IN_DIM * 2;      // 256 KiB

  k0_wt<<<dim3(128), dim3(1024), 0, stream>>>(W, Wt);
  k1_proj<<<dim3(256), dim3(512), 0, stream>>>(x, Wt, a, adj, WxT, s_src,
                                               d_dst, mask);
  k3_attn<<<dim3(16, NH, 4), dim3(512), 0, stream>>>(mask, WxT, s_src, d_dst,
                                                     Pp, Sp);
  k4_final<<<dim3(256), dim3(256), 0, stream>>>(Pp, Sp, gamma, beta, out);
}

// Round 20
// 50.066 us; speedup vs baseline: 2.8000x; 1.0856x over previous
//
#include <hip/hip_runtime.h>
#include <hip/hip_bf16.h>

#define NN 4096
#define IN_DIM 512
#define OUT_DIM 256
#define NH 4
#define HD 64
#define NEG_SLOPE 0.2f
#define LN_EPS 1e-5f
#define LOG2E 1.4426950408889634f
#define MDC 8.0f   // constant softmax stabilizer (log2 domain); valid upper bound

typedef __attribute__((ext_vector_type(8))) short short8;
typedef __attribute__((ext_vector_type(4))) float f32x4;
typedef unsigned short u16;
typedef unsigned int u32;
typedef unsigned char u8;

// ---------------------------------------------------------------------------
// K1: MFMA projection with ALL-LDS operands + in-block W transpose + adj->mask
// pack via wave specialization. grid 256 = (64-row i-tile = bx>>2, head h =
// bx&3), block 512 = 8 waves: waves 0-3 compute (16 rows each, head h, A and
// B both from LDS); waves 4-7 pack rows i0+h*16..+16 (1x coverage across the
// 4 head-blocks of each tile). Staging: x tile 64 KB (f32->bf16, swizzled) +
// W head-slice transposed in-block W[h][k][d] -> wl[d][k] (bf16, swizzled;
// lane=d coalesced 256B reads, ds_write_b128). No k0 kernel, no global Wt.
// ---------------------------------------------------------------------------
__global__ __launch_bounds__(512) void k1_proj(
    const float* __restrict__ x, const float* __restrict__ W,
    const float* __restrict__ a, const int* __restrict__ adj,
    u16* __restrict__ WxT,
    float* __restrict__ s_src,
    float* __restrict__ d_dst,
    u8* __restrict__ mask)
{
  const int h = blockIdx.x & 3;
  const int i0 = (blockIdx.x >> 2) * 64;
  const int t = threadIdx.x;
  const int wv = t >> 6;
  const int lane = t & 63;
  const int rloc = lane & 15;
  const int g = lane >> 4;

  __shared__ u16 xl[64 * 512];   // 64 KiB: x rows i0..i0+63, swizzled units
  __shared__ u16 wl[64 * 512];   // 64 KiB: W^T rows d=0..63, swizzled units

  // ---- stage x tile: 4096 (row,unit) pairs over 512 threads x 8 passes ----
#pragma unroll
  for (int p = 0; p < 8; ++p) {
    const int n = p * 512 + t;
    const int r = n >> 6;
    const int u = n & 63;
    const int phys = (u & 56) | ((u & 7) ^ (r & 7));
    const float* xr = x + (size_t)(i0 + r) * IN_DIM + u * 8;
    const float4 lo = *reinterpret_cast<const float4*>(xr);
    const float4 hi = *reinterpret_cast<const float4*>(xr + 4);
    const float fv[8] = {lo.x, lo.y, lo.z, lo.w, hi.x, hi.y, hi.z, hi.w};
    u16 us[8];
#pragma unroll
    for (int e = 0; e < 8; ++e) {
      __hip_bfloat16 bv = __float2bfloat16(fv[e]);
      us[e] = *reinterpret_cast<const u16*>(&bv);
    }
    uint4 pk;
    pk.x = (u32)us[0] | ((u32)us[1] << 16);
    pk.y = (u32)us[2] | ((u32)us[3] << 16);
    pk.z = (u32)us[4] | ((u32)us[5] << 16);
    pk.w = (u32)us[6] | ((u32)us[7] << 16);
    *reinterpret_cast<uint4*>(&xl[r * 512 + phys * 8]) = pk;
  }

  // ---- stage W^T: wave w covers k = w*64..+63; lane = d (coalesced) ----
  {
#pragma unroll
    for (int u0 = 0; u0 < 8; ++u0) {
      const int ub = wv * 8 + u0;            // 16B-unit index = k/8
      u16 us[8];
#pragma unroll
      for (int e = 0; e < 8; ++e) {
        const float wf = W[((size_t)h * IN_DIM + ub * 8 + e) * HD + lane];
        __hip_bfloat16 bv = __float2bfloat16(wf);
        us[e] = *reinterpret_cast<const u16*>(&bv);
      }
      const int phys = (ub & 56) | ((ub & 7) ^ (lane & 7));
      uint4 pk;
      pk.x = (u32)us[0] | ((u32)us[1] << 16);
      pk.y = (u32)us[2] | ((u32)us[3] << 16);
      pk.z = (u32)us[4] | ((u32)us[5] << 16);
      pk.w = (u32)us[6] | ((u32)us[7] << 16);
      *reinterpret_cast<uint4*>(&wl[lane * 512 + phys * 8]) = pk;
    }
  }
  __syncthreads();

  if (wv >= 4) {
    // ---- pack waves: rows i0+h*16 .. +16, thread t2 covers cols [t2*16,+16)
    const int t2 = t - 256;
    const int j0 = t2 * 16;
    const int prow0 = i0 + h * 16;
#pragma unroll
    for (int rr = 0; rr < 16; ++rr) {
      const int row = prow0 + rr;
      const int* ap = adj + (size_t)row * NN + j0;
      u32 bb = 0;
#pragma unroll
      for (int q = 0; q < 4; ++q) {
        const int4 v = *reinterpret_cast<const int4*>(ap + q * 4);
        const int vj = j0 + q * 4;
        if ((v.x > 0) || (row == vj))     bb |= 1u << (q * 4);
        if ((v.y > 0) || (row == vj + 1)) bb |= 1u << (q * 4 + 1);
        if ((v.z > 0) || (row == vj + 2)) bb |= 1u << (q * 4 + 2);
        if ((v.w > 0) || (row == vj + 3)) bb |= 1u << (q * 4 + 3);
      }
      *reinterpret_cast<u16*>(mask + (size_t)row * (NN / 8) + t2 * 2) = (u16)bb;
    }
    return;
  }

  // ---- compute waves: rows rbase..rbase+16, all-LDS MFMA loop [r9 verified]
  const int rbase = wv * 16;
  f32x4 acc[4] = {};
#pragma unroll
  for (int ks = 0; ks < 16; ++ks) {
    const int u = ks * 4 + g;
    const int ar = rbase + rloc;
    const int aphys = (u & 56) | ((u & 7) ^ (ar & 7));
    const short8 af = *reinterpret_cast<const short8*>(&xl[ar * 512 + aphys * 8]);
#pragma unroll
    for (int dt = 0; dt < 4; ++dt) {
      const int br = dt * 16 + rloc;
      const int bphys = (u & 56) | ((u & 7) ^ (br & 7));
      const short8 bf = *reinterpret_cast<const short8*>(&wl[br * 512 + bphys * 8]);
      acc[dt] = __builtin_amdgcn_mfma_f32_16x16x32_bf16(af, bf, acc[dt], 0, 0, 0);
    }
  }

  // ---- epilogue: WxT store (acc[dt][q] = C[i=rbase+g*4+q][d=dt*16+rloc]) ----
#pragma unroll
  for (int dt = 0; dt < 4; ++dt) {
    u16 us[4];
#pragma unroll
    for (int q = 0; q < 4; ++q) {
      __hip_bfloat16 bv = __float2bfloat16(acc[dt][q]);
      us[q] = *reinterpret_cast<const u16*>(&bv);
    }
    ushort4 pk = {us[0], us[1], us[2], us[3]};
    *reinterpret_cast<ushort4*>(
        WxT + (size_t)(h * HD + dt * 16 + rloc) * NN + i0 + rbase + g * 4) = pk;
  }

  // ---- scores ----
  float as_v[4], ad_v[4];
#pragma unroll
  for (int dt = 0; dt < 4; ++dt) {
    as_v[dt] = a[(size_t)h * 2 * HD + dt * 16 + rloc];
    ad_v[dt] = a[(size_t)h * 2 * HD + HD + dt * 16 + rloc];
  }
  float sv[4], dv[4];
#pragma unroll
  for (int q = 0; q < 4; ++q) {
    float s = 0.f, d = 0.f;
#pragma unroll
    for (int dt = 0; dt < 4; ++dt) {
      s = fmaf(acc[dt][q], as_v[dt], s);
      d = fmaf(acc[dt][q], ad_v[dt], d);
    }
    sv[q] = s; dv[q] = d;
  }
#pragma unroll
  for (int mm = 8; mm >= 1; mm >>= 1) {
#pragma unroll
    for (int q = 0; q < 4; ++q) {
      sv[q] += __shfl_xor(sv[q], mm);
      dv[q] += __shfl_xor(dv[q], mm);
    }
  }
  if (rloc == 0) {
#pragma unroll
    for (int q = 0; q < 4; ++q) {
      const int i = i0 + rbase + g * 4 + q;
      s_src[(size_t)h * NN + i] = sv[q] * LOG2E;
      d_dst[(size_t)h * NN + i] = dv[q] * LOG2E;
    }
  }
}

// ---------------------------------------------------------------------------
// K3: masked rank-1 softmax via block-local E-tables (LDS) + PV (bf16 MFMA),
// LDS-staged & double-buffered [round-15 verified, best config].
// grid (16 i-blocks, 4 heads, 4 j-quarters), block 512 = 8 waves x 32 rows.
// ---------------------------------------------------------------------------
__global__ __launch_bounds__(512) void k3_attn(
    const u8* __restrict__ mask,
    const u16* __restrict__ WxT,
    const float* __restrict__ s_src, const float* __restrict__ d_dst,
    u16* __restrict__ Pp, float* __restrict__ Sp)
{
  const int bx = blockIdx.x;
  const int h = blockIdx.y;
  const int jq = blockIdx.z;
  const int t = threadIdx.x;
  const int wv = t >> 6;
  const int lane = t & 63;
  const int rloc = lane & 15;
  const int g = lane >> 4;
  const int i_base = bx * 256 + wv * 32;

  __shared__ u16 wt[2][64 * 128];   // [buf][row*128 + unit*8], XOR-swizzled
  __shared__ u32 mk[256 * 36];      // [row][36 words] (32 used, pad 4)
  __shared__ float el[1024 * 2];    // (E1,E2) interleaved, 8 KiB

  const float md = MDC;
  const float si0 = s_src[(size_t)h * NN + i_base + rloc];
  const float si1 = s_src[(size_t)h * NN + i_base + 16 + rloc];
  const float e00 = si0 + md, e01 = si1 + md;
  const float m0 = fmaxf(e00, NEG_SLOPE * e00);
  const float m1 = fmaxf(e01, NEG_SLOPE * e01);
  const float sa0 = si0 - m0, sb0 = fmaf(NEG_SLOPE, si0, -m0);
  const float sa1 = si1 - m1, sb1 = fmaf(NEG_SLOPE, si1, -m1);
  float c1_0, c2_0, c1_1, c2_1;
  asm("v_exp_f32 %0, %1" : "=v"(c1_0) : "v"(sa0));
  asm("v_exp_f32 %0, %1" : "=v"(c2_0) : "v"(sb0));
  asm("v_exp_f32 %0, %1" : "=v"(c1_1) : "v"(sa1));
  asm("v_exp_f32 %0, %1" : "=v"(c2_1) : "v"(sb1));

  const u16* wsrc = WxT + (size_t)(h * HD) * NN + jq * 1024;

  const int r0 = t >> 4;
  const int un = t & 15;
  const int up = un ^ (r0 & 7);

  // ---- prologue: E-table gen + mask + WxT tile 0 ----
#pragma unroll
  for (int p = 0; p < 2; ++p) {
    const int j = p * 512 + t;
    const float dj = d_dst[(size_t)h * NN + jq * 1024 + j];
    const float djs = dj * NEG_SLOPE;
    float e1, e2;
    asm("v_exp_f32 %0, %1" : "=v"(e1) : "v"(dj));    // 2^dj
    asm("v_exp_f32 %0, %1" : "=v"(e2) : "v"(djs));   // 2^(0.2 dj)
    el[j * 2] = e1;
    el[j * 2 + 1] = e2;
  }
#pragma unroll
  for (int k = 0; k < 4; ++k) {
    const int n = k * 512 + t;
    const int row = n >> 3;
    const int quad = n & 7;
    const uint4 mv = *reinterpret_cast<const uint4*>(
        mask + ((size_t)(bx * 256 + row) * (NN / 8)) + jq * 128 + quad * 16);
    *reinterpret_cast<uint4*>(&mk[row * 36 + quad * 4]) = mv;
  }
  {
    const uint4 s0 = *reinterpret_cast<const uint4*>(wsrc + (size_t)r0 * NN + un * 8);
    const uint4 s1 = *reinterpret_cast<const uint4*>(wsrc + (size_t)(r0 + 32) * NN + un * 8);
    *reinterpret_cast<uint4*>(&wt[0][r0 * 128 + up * 8]) = s0;
    *reinterpret_cast<uint4*>(&wt[0][(r0 + 32) * 128 + up * 8]) = s1;
  }
  __syncthreads();

  f32x4 acc0[4] = {}, acc1[4] = {};
  f32x4 accs0 = {}, accs1 = {};
  short8 ones;
#pragma unroll
  for (int e = 0; e < 8; ++e) ones[e] = (short)0x3F80;

  int buf = 0;
  for (int tile = 0; tile < 8; ++tile) {
    uint4 n0, n1;
    const bool pf = (tile < 7);
    if (pf) {
      n0 = *reinterpret_cast<const uint4*>(
          wsrc + (size_t)r0 * NN + (tile + 1) * 128 + un * 8);
      n1 = *reinterpret_cast<const uint4*>(
          wsrc + (size_t)(r0 + 32) * NN + (tile + 1) * 128 + un * 8);
    }

    const uint4 mq0 = *reinterpret_cast<const uint4*>(
        &mk[(wv * 32 + rloc) * 36 + tile * 4]);
    const uint4 mq1 = *reinterpret_cast<const uint4*>(
        &mk[(wv * 32 + 16 + rloc) * 36 + tile * 4]);
#pragma unroll
    for (int ks = 0; ks < 4; ++ks) {
      short8 bfr[4];
#pragma unroll
      for (int dt = 0; dt < 4; ++dt) {
        const int row = dt * 16 + rloc;
        const int unit = (ks * 4 + g) ^ (row & 7);
        bfr[dt] = *reinterpret_cast<const short8*>(&wt[buf][row * 128 + unit * 8]);
      }
      const int jloc = tile * 128 + ks * 32 + g * 8;
      const float* eb = &el[2 * jloc];
      const float4 Ea = *reinterpret_cast<const float4*>(eb);
      const float4 Eb = *reinterpret_cast<const float4*>(eb + 4);
      const float4 Ec = *reinterpret_cast<const float4*>(eb + 8);
      const float4 Ed = *reinterpret_cast<const float4*>(eb + 12);
      const float E1v[8] = {Ea.x, Ea.z, Eb.x, Eb.z, Ec.x, Ec.z, Ed.x, Ed.z};
      const float E2v[8] = {Ea.y, Ea.w, Eb.y, Eb.w, Ec.y, Ec.w, Ed.y, Ed.w};
      const u32 mw0 = (ks == 0) ? mq0.x : (ks == 1) ? mq0.y : (ks == 2) ? mq0.z : mq0.w;
      const u32 mw1 = (ks == 0) ? mq1.x : (ks == 1) ? mq1.y : (ks == 2) ? mq1.z : mq1.w;
      const u32 mb0 = (mw0 >> (g * 8)) & 0xffu;
      const u32 mb1 = (mw1 >> (g * 8)) & 0xffu;
      short8 af0, af1;
#pragma unroll
      for (int e = 0; e < 8; ++e) {
        float p0 = fmaxf(c1_0 * E1v[e], c2_0 * E2v[e]);
        float p1 = fmaxf(c1_1 * E1v[e], c2_1 * E2v[e]);
        p0 = (mb0 & (1u << e)) ? p0 : 0.f;
        p1 = (mb1 & (1u << e)) ? p1 : 0.f;
        __hip_bfloat16 b0 = __float2bfloat16(p0);
        __hip_bfloat16 b1 = __float2bfloat16(p1);
        af0[e] = *reinterpret_cast<const short*>(&b0);
        af1[e] = *reinterpret_cast<const short*>(&b1);
      }
#pragma unroll
      for (int dt = 0; dt < 4; ++dt) {
        acc0[dt] = __builtin_amdgcn_mfma_f32_16x16x32_bf16(af0, bfr[dt], acc0[dt], 0, 0, 0);
        acc1[dt] = __builtin_amdgcn_mfma_f32_16x16x32_bf16(af1, bfr[dt], acc1[dt], 0, 0, 0);
      }
      accs0 = __builtin_amdgcn_mfma_f32_16x16x32_bf16(af0, ones, accs0, 0, 0, 0);
      accs1 = __builtin_amdgcn_mfma_f32_16x16x32_bf16(af1, ones, accs1, 0, 0, 0);
    }

    if (pf) {
      *reinterpret_cast<uint4*>(&wt[buf ^ 1][r0 * 128 + up * 8]) = n0;
      *reinterpret_cast<uint4*>(&wt[buf ^ 1][(r0 + 32) * 128 + up * 8]) = n1;
    }
    __syncthreads();
    buf ^= 1;
  }

  u16* Pb = Pp + (size_t)jq * NN * OUT_DIM;
#pragma unroll
  for (int dt = 0; dt < 4; ++dt)
#pragma unroll
    for (int q = 0; q < 4; ++q) {
      __hip_bfloat16 v0 = __float2bfloat16(acc0[dt][q]);
      __hip_bfloat16 v1 = __float2bfloat16(acc1[dt][q]);
      Pb[(size_t)(i_base + g * 4 + q) * OUT_DIM + h * HD + dt * 16 + rloc] =
          *reinterpret_cast<const u16*>(&v0);
      Pb[(size_t)(i_base + 16 + g * 4 + q) * OUT_DIM + h * HD + dt * 16 + rloc] =
          *reinterpret_cast<const u16*>(&v1);
    }
  if (rloc == 0) {
    *reinterpret_cast<f32x4*>(&Sp[((size_t)jq * NH + h) * NN + i_base + g * 4]) = accs0;
    *reinterpret_cast<f32x4*>(&Sp[((size_t)jq * NH + h) * NN + i_base + 16 + g * 4]) = accs1;
  }
}

// ---------------------------------------------------------------------------
// K4: merge 4 j-quarter partials, normalize, ELU, LayerNorm, store.
// [round-7 verified]
// ---------------------------------------------------------------------------
__global__ __launch_bounds__(256) void k4_final(
    const u16* __restrict__ Pp, const float* __restrict__ Sp,
    const float* __restrict__ gamma, const float* __restrict__ beta,
    float* __restrict__ out)
{
  const int i0 = blockIdx.x * 16;
  const int t = threadIdx.x;
  const int wv = t >> 6;
  const int lane = t & 63;
  const int c0 = lane * 4;
  const int h = lane >> 4;

  const float4 gm = *reinterpret_cast<const float4*>(gamma + c0);
  const float4 bt = *reinterpret_cast<const float4*>(beta + c0);

  for (int rr = 0; rr < 4; ++rr) {
    const int i = i0 + wv * 4 + rr;
    float v[4] = {0.f, 0.f, 0.f, 0.f};
    float denom = 0.f;
#pragma unroll
    for (int q = 0; q < 4; ++q) {
      const ushort4 pv = *reinterpret_cast<const ushort4*>(
          Pp + (size_t)q * NN * OUT_DIM + (size_t)i * OUT_DIM + c0);
      v[0] += __uint_as_float((u32)pv.x << 16);
      v[1] += __uint_as_float((u32)pv.y << 16);
      v[2] += __uint_as_float((u32)pv.z << 16);
      v[3] += __uint_as_float((u32)pv.w << 16);
      denom += Sp[((size_t)q * NH + h) * NN + i];
    }
    const float inv = 1.f / denom;
    float sum = 0.f, sq = 0.f;
#pragma unroll
    for (int q2 = 0; q2 < 4; ++q2) {
      float xx = v[q2] * inv;
      xx = (xx > 0.f) ? xx : expm1f(xx);
      v[q2] = xx;
      sum += xx;
      sq += xx * xx;
    }
#pragma unroll
    for (int mm = 32; mm >= 1; mm >>= 1) {
      sum += __shfl_xor(sum, mm);
      sq += __shfl_xor(sq, mm);
    }
    const float mu = sum * (1.f / OUT_DIM);
    const float var = sq * (1.f / OUT_DIM) - mu * mu;
    const float rs = rsqrtf(var + LN_EPS);
    float4 o;
    o.x = (v[0] - mu) * rs * gm.x + bt.x;
    o.y = (v[1] - mu) * rs * gm.y + bt.y;
    o.z = (v[2] - mu) * rs * gm.z + bt.z;
    o.w = (v[3] - mu) * rs * gm.w + bt.w;
    *reinterpret_cast<float4*>(out + (size_t)i * OUT_DIM + c0) = o;
  }
}

extern "C" void kernel_launch(void* const* d_in, const int* in_sizes, int n_in,
                              void* d_out, int out_size, void* d_ws, size_t ws_size,
                              hipStream_t stream) {
  const float* x = (const float*)d_in[0];
  const int* adj = (const int*)d_in[1];
  const float* W = (const float*)d_in[2];
  const float* a = (const float*)d_in[3];
  const float* gamma = (const float*)d_in[4];
  const float* beta = (const float*)d_in[5];
  float* out = (float*)d_out;

  char* ws = (char*)d_ws;
  size_t off = 0;
  u16* WxT = (u16*)(ws + off);        off += (size_t)NH * HD * NN * 2;          // 2 MiB
  float* s_src = (float*)(ws + off);  off += (size_t)NH * NN * 4;               // 64 KiB
  float* d_dst = (float*)(ws + off);  off += (size_t)NH * NN * 4;               // 64 KiB
  u8* mask = (u8*)(ws + off);         off += (size_t)NN * (NN / 8);             // 2 MiB
  u16* Pp = (u16*)(ws + off);         off += (size_t)4 * NN * OUT_DIM * 2;      // 8 MiB (bf16)
  float* Sp = (float*)(ws + off);     off += (size_t)4 * NH * NN * 4;           // 256 KiB

  k1_proj<<<dim3(256), dim3(512), 0, stream>>>(x, W, a, adj, WxT, s_src,
                                               d_dst, mask);
  k3_attn<<<dim3(16, NH, 4), dim3(512), 0, stream>>>(mask, WxT, s_src, d_dst,
                                                     Pp, Sp);
  k4_final<<<dim3(256), dim3(256), 0, stream>>>(Pp, Sp, gamma, beta, out);
}